// Round 12
// baseline (358.366 us; speedup 1.0000x reference)
//
#include <hip/hip_runtime.h>
#include <hip/hip_bf16.h>
#include <math.h>

// Problem constants (from reference)
constexpr int N_ENT = 100000;
constexpr int NEDGE = 1600000;
constexpr int BATCH = 8192;
constexpr int NBLK_SCAN = (N_ENT + 255) / 256;   // 391

// Bucketed CSR placement
constexpr int NBUCK   = 256;
constexpr int KNODE   = 391;                      // 256*391 >= N_ENT
constexpr int TILE    = 4096;
constexpr int NTILE   = (NEDGE + TILE - 1) / TILE; // 391
constexpr int BUCKCAP = 8192;                     // fixed bucket region

constexpr int NBLK_G = (N_ENT + 63) / 64;         // 1563 (64-row GEMM tiles)

// Column-chunked layer-1 gather table: 4 chunks x 16 cols, 3.2 MB each
// (< 4 MB per-XCD L2 -> chunk stays L2-resident while its blocks run)
constexpr int NCH      = 4;
constexpr int CHROW    = N_ENT + 1;               // + zero row
constexpr int BLK_PER_CH = N_ENT * 64 / 256;      // 25000

// bf16 helpers (RNE pack, exact unpack)
__device__ inline unsigned short f2b(float x) {
    unsigned int u = __float_as_uint(x);
    unsigned int r = (u + 0x7fffu + ((u >> 16) & 1u)) >> 16;
    return (unsigned short)r;
}
__device__ inline float b2f(unsigned short h) {
    return __uint_as_float(((unsigned int)h) << 16);
}
__device__ inline float blo(unsigned int p) { return __uint_as_float(p << 16); }
__device__ inline float bhi(unsigned int p) { return __uint_as_float(p & 0xffff0000u); }

// ---------------------------------------------------------------------------
// Workspace layout (4-byte units):
//  degi      : [0, 100000)
//  dinv      : [100000, 200000)
//  row_start : [200000, 300001)
//  gcursor   : [300004, 300260)
//  partials  : [300264, 300655)
//  srcs      : [300656, 1900656)
//  emb_c     : [1900656, 5100688)   ushort[4][N+1][16] column-chunked
//  z / h2b   : [5100688, 11500688)  float [N,64]; h2b (ushort[(N+1)*64]) reuses
//  y1r/temp  : [11500688, 24300688) float [N,128]; temp overlaps (dead until gemm1)

// K1: prep — dinv + premultiplied bf16 entity rows, column-chunked layout
__global__ __launch_bounds__(256) void prep_k(const float* __restrict__ emb,
                                              const int* __restrict__ degi,
                                              float* __restrict__ dinv,
                                              unsigned short* __restrict__ emb_c) {
    int gt   = blockIdx.x * 256 + threadIdx.x;
    int n    = gt >> 6;
    int lane = threadIdx.x & 63;
    if (n > N_ENT) return;
    int ch = lane >> 4, li = lane & 15;
    size_t slot = ((size_t)ch * CHROW + n) * 16 + li;
    if (n == N_ENT) { emb_c[slot] = 0; return; }
    float v = emb[(size_t)n * 64 + lane];
    float s = v * v;
#pragma unroll
    for (int o = 32; o > 0; o >>= 1) s += __shfl_xor(s, o, 64);
    float nrm = sqrtf(s);
    float sc  = nrm > 1.0f ? 1.0f / nrm : 1.0f;
    float dv  = 1.0f / sqrtf((float)(degi[n] + 1));
    if (lane == 0) dinv[n] = dv;
    emb_c[slot] = f2b(sc * dv * v);
}

// K0a: gcursor init to fixed bucket bases
__global__ __launch_bounds__(256) void ginit_k(int* __restrict__ gcursor) {
    gcursor[threadIdx.x] = threadIdx.x * BUCKCAP;
}

// K0b: bucket binning into fixed-capacity regions
__global__ __launch_bounds__(256) void bin_k(const int* __restrict__ edges,
                                             int* __restrict__ gcursor,
                                             unsigned int* __restrict__ temp) {
    __shared__ int cnt[NBUCK];
    __shared__ int gb[NBUCK];
    __shared__ int off[NBUCK];
    int tid  = threadIdx.x;
    int base = blockIdx.x * TILE;
    int sv[16], dv[16], bv[16];
    cnt[tid] = 0;
    __syncthreads();
#pragma unroll
    for (int i = 0; i < 16; ++i) {
        int e = base + i * 256 + tid;
        if (e < NEDGE) {
            sv[i] = edges[e];
            dv[i] = edges[NEDGE + e];
            bv[i] = dv[i] / KNODE;
            atomicAdd(&cnt[bv[i]], 1);
        } else {
            bv[i] = -1;
        }
    }
    __syncthreads();
    if (cnt[tid] > 0) gb[tid] = atomicAdd(&gcursor[tid], cnt[tid]);
    off[tid] = 0;
    __syncthreads();
#pragma unroll
    for (int i = 0; i < 16; ++i) {
        int b = bv[i];
        if (b >= 0) {
            int p  = atomicAdd(&off[b], 1);
            int dl = dv[i] - b * KNODE;
            temp[gb[b] + p] = ((unsigned int)sv[i] << 9) | (unsigned int)dl;
        }
    }
}

// K0c: per-bucket degree histogram from binned temp
__global__ __launch_bounds__(256) void count_k(const unsigned int* __restrict__ temp,
                                               const int* __restrict__ gcursor,
                                               int* __restrict__ degi) {
    __shared__ int cnt[KNODE];
    int b     = blockIdx.x;
    int node0 = b * KNODE;
    int nn    = N_ENT - node0; if (nn > KNODE) nn = KNODE;
    for (int i = threadIdx.x; i < KNODE; i += 256) cnt[i] = 0;
    __syncthreads();
    int tbeg = b * BUCKCAP;
    int tend = gcursor[b];
    for (int idx = tbeg + threadIdx.x; idx < tend; idx += 256)
        atomicAdd(&cnt[temp[idx] & 511u], 1);
    __syncthreads();
    for (int i = threadIdx.x; i < nn; i += 256) degi[node0 + i] = cnt[i];
}

// K3a/b/c: hierarchical exclusive scan of degi -> row_start
__global__ __launch_bounds__(256) void scan_partials(const int* __restrict__ degi,
                                                     int* __restrict__ partials) {
    __shared__ int ws[4];
    int i = blockIdx.x * 256 + threadIdx.x;
    int v = (i < N_ENT) ? degi[i] : 0;
#pragma unroll
    for (int o = 32; o > 0; o >>= 1) v += __shfl_xor(v, o, 64);
    if ((threadIdx.x & 63) == 0) ws[threadIdx.x >> 6] = v;
    __syncthreads();
    if (threadIdx.x == 0) partials[blockIdx.x] = ws[0] + ws[1] + ws[2] + ws[3];
}

__global__ __launch_bounds__(512) void scan_offsets(int* __restrict__ partials,
                                                    int* __restrict__ row_start) {
    __shared__ int ts[512];
    int t = threadIdx.x;
    int v = (t < NBLK_SCAN) ? partials[t] : 0;
    ts[t] = v;
    __syncthreads();
    for (int off = 1; off < 512; off <<= 1) {
        int x = (t >= off) ? ts[t - off] : 0;
        __syncthreads();
        ts[t] += x;
        __syncthreads();
    }
    if (t < NBLK_SCAN) partials[t] = ts[t] - v;
    if (t == 0) row_start[N_ENT] = NEDGE;
}

__global__ __launch_bounds__(256) void scan_apply(const int* __restrict__ degi,
                                                  const int* __restrict__ partials,
                                                  int* __restrict__ row_start) {
    __shared__ int ts[256];
    int t = threadIdx.x;
    int i = blockIdx.x * 256 + t;
    int v = (i < N_ENT) ? degi[i] : 0;
    ts[t] = v;
    __syncthreads();
    for (int off = 1; off < 256; off <<= 1) {
        int x = (t >= off) ? ts[t - off] : 0;
        __syncthreads();
        ts[t] += x;
        __syncthreads();
    }
    if (i < N_ENT) row_start[i] = ts[t] - v + partials[blockIdx.x];
}

// K4b: within-bucket placement
__global__ __launch_bounds__(256) void unbin_k(const unsigned int* __restrict__ temp,
                                               const int* __restrict__ gcursor,
                                               const int* __restrict__ row_start,
                                               int* __restrict__ srcs) {
    __shared__ int cur[KNODE];
    int b     = blockIdx.x;
    int node0 = b * KNODE;
    int nn    = N_ENT - node0; if (nn > KNODE) nn = KNODE;
    for (int i = threadIdx.x; i < nn; i += 256) cur[i] = row_start[node0 + i];
    __syncthreads();
    int tbeg = b * BUCKCAP;
    int tend = gcursor[b];
    for (int idx = tbeg + threadIdx.x; idx < tend; idx += 256) {
        unsigned int v = temp[idx];
        int dl = (int)(v & 511u);
        int s  = (int)(v >> 9);
        int pos = atomicAdd(&cur[dl], 1);
        srcs[pos] = s;
    }
}

// K5: layer-1 aggregate, column-chunked: grid = NCH * BLK_PER_CH; chunk c
// = blockIdx/BLK_PER_CH so in-flight blocks share one 3.2 MB L2-resident
// chunk. 8 edges per gather instruction (8 slots x 8 lanes x uint=2 cols).
__global__ __launch_bounds__(256) void reduce1_k(const int* __restrict__ row_start,
                                                 const int* __restrict__ srcs,
                                                 const unsigned short* __restrict__ emb_c,
                                                 const float* __restrict__ dinv,
                                                 float* __restrict__ z) {
    int c     = blockIdx.x / BLK_PER_CH;
    int local = blockIdx.x - c * BLK_PER_CH;
    int gt    = local * 256 + threadIdx.x;
    int dst   = gt >> 6;
    int lane  = threadIdx.x & 63;
    int sub   = lane >> 3;        // edge slot 0..7
    int li    = lane & 7;         // uint covers cols 2*li, 2*li+1 of chunk
    const unsigned short* tab = emb_c + (size_t)c * CHROW * 16;
    int beg = row_start[dst];
    int end = row_start[dst + 1];
    float ax = 0.f, ay = 0.f;
    for (int base = beg; base < end; base += 64) {
        int cnt = end - base; if (cnt > 64) cnt = 64;
        int s_v = (base + lane < end) ? srcs[base + lane] : N_ENT;
        for (int jj = 0; jj < cnt; jj += 16) {
            int s0 = __shfl(s_v, jj + sub,     64);
            int s1 = __shfl(s_v, jj + 8 + sub, 64);
            unsigned int p0 = *(const unsigned int*)(tab + (size_t)s0 * 16 + li * 2);
            unsigned int p1 = *(const unsigned int*)(tab + (size_t)s1 * 16 + li * 2);
            ax += blo(p0) + blo(p1);
            ay += bhi(p0) + bhi(p1);
        }
    }
    // sum the 8 edge-slots
    ax += __shfl_xor(ax, 8, 64);  ay += __shfl_xor(ay, 8, 64);
    ax += __shfl_xor(ax, 16, 64); ay += __shfl_xor(ay, 16, 64);
    ax += __shfl_xor(ax, 32, 64); ay += __shfl_xor(ay, 32, 64);
    if (lane < 8) {
        unsigned int po = *(const unsigned int*)(tab + (size_t)dst * 16 + li * 2);
        float dv = dinv[dst];
        float2 o;
        o.x = dv * (ax + blo(po));
        o.y = dv * (ay + bhi(po));
        *(float2*)(z + (size_t)dst * 64 + c * 16 + li * 2) = o;
    }
}

// K6: y1r = relu(z @ W1 + b1)  [N,64]@[64,128] — register-blocked 8x4/thread.
__global__ __launch_bounds__(256) void gemm1_relu(const float* __restrict__ z,
                                                  const float* __restrict__ W1g,
                                                  const float* __restrict__ b1,
                                                  float* __restrict__ y1r) {
    __shared__ float As[64 * 68];
    __shared__ float Ws[64 * 132];
    int tid  = threadIdx.x;
    int row0 = blockIdx.x * 64;
    for (int idx = tid; idx < 1024; idx += 256) {
        int r = idx >> 4, c4 = (idx & 15) * 4;
        int grow = row0 + r;
        float4 v = make_float4(0.f, 0.f, 0.f, 0.f);
        if (grow < N_ENT) v = *(const float4*)(z + (size_t)grow * 64 + c4);
        *(float4*)(As + r * 68 + c4) = v;
    }
    for (int idx = tid; idx < 2048; idx += 256) {
        int k = idx >> 5, c4 = (idx & 31) * 4;
        *(float4*)(Ws + k * 132 + c4) = *(const float4*)(W1g + k * 128 + c4);
    }
    __syncthreads();

    int cg = tid & 31;
    int rg = tid >> 5;
    int c0 = cg * 4;
    int r0 = rg * 8;
    const float4* A4 = (const float4*)As;   // row stride 17
    const float4* W4 = (const float4*)Ws;   // row stride 33
    float acc[8][4];
#pragma unroll
    for (int i = 0; i < 8; ++i)
#pragma unroll
        for (int j = 0; j < 4; ++j) acc[i][j] = 0.f;

    for (int k4 = 0; k4 < 16; ++k4) {
        float4 w0 = W4[(4 * k4 + 0) * 33 + cg];
        float4 w1 = W4[(4 * k4 + 1) * 33 + cg];
        float4 w2 = W4[(4 * k4 + 2) * 33 + cg];
        float4 w3 = W4[(4 * k4 + 3) * 33 + cg];
#pragma unroll
        for (int i = 0; i < 8; ++i) {
            float4 a = A4[(r0 + i) * 17 + k4];
            acc[i][0] += a.x * w0.x + a.y * w1.x + a.z * w2.x + a.w * w3.x;
            acc[i][1] += a.x * w0.y + a.y * w1.y + a.z * w2.y + a.w * w3.y;
            acc[i][2] += a.x * w0.z + a.y * w1.z + a.z * w2.z + a.w * w3.z;
            acc[i][3] += a.x * w0.w + a.y * w1.w + a.z * w2.w + a.w * w3.w;
        }
    }
    float4 bb = *(const float4*)(b1 + c0);
#pragma unroll
    for (int i = 0; i < 8; ++i) {
        int grow = row0 + r0 + i;
        if (grow < N_ENT) {
            float4 o;
            o.x = fmaxf(acc[i][0] + bb.x, 0.f);
            o.y = fmaxf(acc[i][1] + bb.y, 0.f);
            o.z = fmaxf(acc[i][2] + bb.z, 0.f);
            o.w = fmaxf(acc[i][3] + bb.w, 0.f);
            *(float4*)(y1r + (size_t)grow * 128 + c0) = o;
        }
    }
}

// K7: h2b = bf16(dinv[row]*(y1r @ W2))  [N,128]@[128,64] — 4x4/thread.
// Also writes the zero row at grow == N_ENT for reduce2f's OOB slots.
__global__ __launch_bounds__(256) void gemm2_k(const float* __restrict__ y1r,
                                               const float* __restrict__ W2g,
                                               const float* __restrict__ dinv,
                                               unsigned short* __restrict__ h2b) {
    __shared__ float Ys[64 * 132];
    __shared__ float Ws[128 * 68];
    int tid  = threadIdx.x;
    int row0 = blockIdx.x * 64;
    for (int idx = tid; idx < 2048; idx += 256) {
        int r = idx >> 5, c4 = (idx & 31) * 4;
        int grow = row0 + r;
        float4 v = make_float4(0.f, 0.f, 0.f, 0.f);
        if (grow < N_ENT) v = *(const float4*)(y1r + (size_t)grow * 128 + c4);
        *(float4*)(Ys + r * 132 + c4) = v;
    }
    for (int idx = tid; idx < 2048; idx += 256) {
        int k = idx >> 4, c4 = (idx & 15) * 4;
        *(float4*)(Ws + k * 68 + c4) = *(const float4*)(W2g + k * 64 + c4);
    }
    __syncthreads();

    int cg = tid & 15;
    int rg = tid >> 4;
    int c0 = cg * 4;
    int r0 = rg * 4;
    const float4* Y4 = (const float4*)Ys;   // row stride 33
    const float4* W4 = (const float4*)Ws;   // row stride 17
    float acc[4][4];
#pragma unroll
    for (int i = 0; i < 4; ++i)
#pragma unroll
        for (int j = 0; j < 4; ++j) acc[i][j] = 0.f;

    for (int k4 = 0; k4 < 32; ++k4) {
        float4 w0 = W4[(4 * k4 + 0) * 17 + cg];
        float4 w1 = W4[(4 * k4 + 1) * 17 + cg];
        float4 w2 = W4[(4 * k4 + 2) * 17 + cg];
        float4 w3 = W4[(4 * k4 + 3) * 17 + cg];
#pragma unroll
        for (int i = 0; i < 4; ++i) {
            float4 a = Y4[(r0 + i) * 33 + k4];
            acc[i][0] += a.x * w0.x + a.y * w1.x + a.z * w2.x + a.w * w3.x;
            acc[i][1] += a.x * w0.y + a.y * w1.y + a.z * w2.y + a.w * w3.y;
            acc[i][2] += a.x * w0.z + a.y * w1.z + a.z * w2.z + a.w * w3.z;
            acc[i][3] += a.x * w0.w + a.y * w1.w + a.z * w2.w + a.w * w3.w;
        }
    }
#pragma unroll
    for (int i = 0; i < 4; ++i) {
        int grow = row0 + r0 + i;
        if (grow < N_ENT) {
            float dv = dinv[grow];
            unsigned int h0 = f2b(acc[i][0] * dv);
            unsigned int h1 = f2b(acc[i][1] * dv);
            unsigned int h2 = f2b(acc[i][2] * dv);
            unsigned int h3 = f2b(acc[i][3] * dv);
            uint2 p;
            p.x = h0 | (h1 << 16);
            p.y = h2 | (h3 << 16);
            *(uint2*)(h2b + (size_t)grow * 64 + c0) = p;
        } else if (grow == N_ENT) {
            uint2 p; p.x = 0u; p.y = 0u;
            *(uint2*)(h2b + (size_t)grow * 64 + c0) = p;
        }
    }
}

// K8: fused layer-2 aggregate + final dot for the 8192 batch items,
// 4 edges per gather instruction.
__global__ __launch_bounds__(256) void reduce2f_k(const int* __restrict__ u,
                                                  const int* __restrict__ iidx,
                                                  const float* __restrict__ uemb,
                                                  const int* __restrict__ row_start,
                                                  const int* __restrict__ srcs,
                                                  const unsigned short* __restrict__ h2b,
                                                  const float* __restrict__ dinv,
                                                  const float* __restrict__ b2,
                                                  float* __restrict__ out) {
    int gt   = blockIdx.x * 256 + threadIdx.x;
    int b    = gt >> 6;
    int lane = threadIdx.x & 63;
    int sub  = lane >> 4;
    int li   = lane & 15;
    int dst = iidx[b];
    int beg = row_start[dst];
    int end = row_start[dst + 1];
    float4 acc = make_float4(0.f, 0.f, 0.f, 0.f);
    for (int base = beg; base < end; base += 64) {
        int cnt = end - base; if (cnt > 64) cnt = 64;
        int s_v = (base + lane < end) ? srcs[base + lane] : N_ENT;
        for (int jj = 0; jj < cnt; jj += 16) {
            int s0 = __shfl(s_v, jj + sub,      64);
            int s1 = __shfl(s_v, jj + 4 + sub,  64);
            int s2 = __shfl(s_v, jj + 8 + sub,  64);
            int s3 = __shfl(s_v, jj + 12 + sub, 64);
            uint2 p0 = *(const uint2*)(h2b + (size_t)s0 * 64 + li * 4);
            uint2 p1 = *(const uint2*)(h2b + (size_t)s1 * 64 + li * 4);
            uint2 p2 = *(const uint2*)(h2b + (size_t)s2 * 64 + li * 4);
            uint2 p3 = *(const uint2*)(h2b + (size_t)s3 * 64 + li * 4);
            acc.x += blo(p0.x) + blo(p1.x) + blo(p2.x) + blo(p3.x);
            acc.y += bhi(p0.x) + bhi(p1.x) + bhi(p2.x) + bhi(p3.x);
            acc.z += blo(p0.y) + blo(p1.y) + blo(p2.y) + blo(p3.y);
            acc.w += bhi(p0.y) + bhi(p1.y) + bhi(p2.y) + bhi(p3.y);
        }
    }
    acc.x += __shfl_xor(acc.x, 16, 64); acc.y += __shfl_xor(acc.y, 16, 64);
    acc.z += __shfl_xor(acc.z, 16, 64); acc.w += __shfl_xor(acc.w, 16, 64);
    acc.x += __shfl_xor(acc.x, 32, 64); acc.y += __shfl_xor(acc.y, 32, 64);
    acc.z += __shfl_xor(acc.z, 32, 64); acc.w += __shfl_xor(acc.w, 32, 64);
    float s1 = 0.f, s2 = 0.f;
    if (lane < 16) {
        uint2 po = *(const uint2*)(h2b + (size_t)dst * 64 + li * 4);
        float dv = dinv[dst];
        float4 bb = *(const float4*)(b2 + li * 4);
        float4 z2v;
        z2v.x = dv * (acc.x + blo(po.x)) + bb.x;
        z2v.y = dv * (acc.y + bhi(po.x)) + bb.y;
        z2v.z = dv * (acc.z + blo(po.y)) + bb.z;
        z2v.w = dv * (acc.w + bhi(po.y)) + bb.w;
        float4 ue = *(const float4*)(uemb + (size_t)u[b] * 64 + li * 4);
        s1 = ue.x * ue.x + ue.y * ue.y + ue.z * ue.z + ue.w * ue.w;
        s2 = ue.x * z2v.x + ue.y * z2v.y + ue.z * z2v.z + ue.w * z2v.w;
    }
#pragma unroll
    for (int o = 8; o > 0; o >>= 1) {
        s1 += __shfl_xor(s1, o, 64);
        s2 += __shfl_xor(s2, o, 64);
    }
    if (lane == 0) {
        float nrm = sqrtf(s1);
        float sc  = nrm > 1.0f ? 1.0f / nrm : 1.0f;
        float uv  = s2 * sc;
        out[b] = 1.0f / (1.0f + expf(-uv));
    }
}

// ---------------------------------------------------------------------------
extern "C" void kernel_launch(void* const* d_in, const int* in_sizes, int n_in,
                              void* d_out, int out_size, void* d_ws, size_t ws_size,
                              hipStream_t stream) {
    const int*   u          = (const int*)d_in[0];
    const int*   iidx       = (const int*)d_in[1];
    const int*   edges      = (const int*)d_in[2];
    const float* user_emb   = (const float*)d_in[3];
    const float* entity_emb = (const float*)d_in[4];
    const float* W1         = (const float*)d_in[5];
    const float* b1         = (const float*)d_in[6];
    const float* W2         = (const float*)d_in[7];
    const float* b2         = (const float*)d_in[8];
    float*       out        = (float*)d_out;

    char* ws = (char*)d_ws;
    int*            degi      = (int*)           (ws);
    float*          dinv      = (float*)         (ws + 100000u * 4);
    int*            row_start = (int*)           (ws + 200000u * 4);
    int*            gcursor   = (int*)           (ws + 300004u * 4);
    int*            partials  = (int*)           (ws + 300264u * 4);
    int*            srcs      = (int*)           (ws + 300656u * 4);
    unsigned short* emb_c     = (unsigned short*)(ws + 1900656u * 4);  // [4][N+1][16]
    float*          z         = (float*)         (ws + 5100688u * 4);
    float*          y1r       = (float*)         (ws + 11500688u * 4);
    unsigned int*   temp      = (unsigned int*)  y1r;  // temp dead before gemm1
    unsigned short* h2b       = (unsigned short*)z;    // z dead after gemm1 ((N+1)*64)

    ginit_k<<<1, 256, 0, stream>>>(gcursor);
    bin_k<<<NTILE, 256, 0, stream>>>(edges, gcursor, temp);
    count_k<<<NBUCK, 256, 0, stream>>>(temp, gcursor, degi);

    prep_k<<<N_ENT * 64 / 256 + 1, 256, 0, stream>>>(entity_emb, degi, dinv, emb_c);

    scan_partials<<<NBLK_SCAN, 256, 0, stream>>>(degi, partials);
    scan_offsets<<<1, 512, 0, stream>>>(partials, row_start);
    scan_apply<<<NBLK_SCAN, 256, 0, stream>>>(degi, partials, row_start);

    unbin_k<<<NBUCK, 256, 0, stream>>>(temp, gcursor, row_start, srcs);

    reduce1_k<<<NCH * BLK_PER_CH, 256, 0, stream>>>(row_start, srcs, emb_c, dinv, z);
    gemm1_relu<<<NBLK_G, 256, 0, stream>>>(z, W1, b1, y1r);
    gemm2_k<<<NBLK_G, 256, 0, stream>>>(y1r, W2, dinv, h2b);

    reduce2f_k<<<BATCH * 64 / 256, 256, 0, stream>>>(u, iidx, user_emb, row_start,
                                                     srcs, h2b, dinv, b2, out);
}

// Round 13
// 325.079 us; speedup vs baseline: 1.1024x; 1.1024x over previous
//
#include <hip/hip_runtime.h>
#include <hip/hip_bf16.h>
#include <math.h>

// Problem constants (from reference)
constexpr int N_ENT = 100000;
constexpr int NEDGE = 1600000;
constexpr int BATCH = 8192;
constexpr int NBLK_SCAN = (N_ENT + 255) / 256;   // 391

// Bucketed CSR placement
constexpr int NBUCK   = 256;
constexpr int KNODE   = 391;                      // 256*391 >= N_ENT
constexpr int TILE    = 4096;
constexpr int NTILE   = (NEDGE + TILE - 1) / TILE; // 391
constexpr int BUCKCAP = 8192;                     // fixed bucket region

constexpr int NBLK_G = (N_ENT + 63) / 64;         // 1563 (64-row GEMM tiles)

// bf16 helpers (RNE pack, exact unpack)
__device__ inline unsigned short f2b(float x) {
    unsigned int u = __float_as_uint(x);
    unsigned int r = (u + 0x7fffu + ((u >> 16) & 1u)) >> 16;
    return (unsigned short)r;
}
__device__ inline float b2f(unsigned short h) {
    return __uint_as_float(((unsigned int)h) << 16);
}
__device__ inline float blo(unsigned int p) { return __uint_as_float(p << 16); }
__device__ inline float bhi(unsigned int p) { return __uint_as_float(p & 0xffff0000u); }

// ---------------------------------------------------------------------------
// Workspace layout (4-byte units): R11 layout.
//  degi      : [0, 100000)
//  dinv      : [100000, 200000)
//  row_start : [200000, 300001)
//  gcursor   : [300004, 300260)
//  partials  : [300264, 300655)
//  srcs      : [300656, 1900656)
//  emb_b     : [1900656, 5100688)   ushort[(N+1)*64] (+ zero row)
//  z / h2b   : [5100688, 11500688)  float [N,64]; h2b (ushort[(N+1)*64]) reuses
//  temp      : [11500688, ...)      uint (dead before gemm12)
// (y1r eliminated — y1 tile lives in LDS inside gemm12_k)

// K1: prep — dinv + premultiplied bf16 entity rows (+ zero row at N_ENT)
// [R11 version — R12's column-chunked variant regressed 2x: instruction
//  count + VALU overhead dominate over L2 residency for this gather]
__global__ __launch_bounds__(256) void prep_k(const float* __restrict__ emb,
                                              const int* __restrict__ degi,
                                              float* __restrict__ dinv,
                                              unsigned short* __restrict__ emb_b) {
    int gt   = blockIdx.x * 256 + threadIdx.x;
    int n    = gt >> 6;
    int lane = threadIdx.x & 63;
    if (n > N_ENT) return;
    if (n == N_ENT) { emb_b[(size_t)n * 64 + lane] = 0; return; }
    float v = emb[(size_t)n * 64 + lane];
    float s = v * v;
#pragma unroll
    for (int o = 32; o > 0; o >>= 1) s += __shfl_xor(s, o, 64);
    float nrm = sqrtf(s);
    float sc  = nrm > 1.0f ? 1.0f / nrm : 1.0f;
    float dv  = 1.0f / sqrtf((float)(degi[n] + 1));
    if (lane == 0) dinv[n] = dv;
    emb_b[(size_t)n * 64 + lane] = f2b(sc * dv * v);
}

// K0a: gcursor init to fixed bucket bases
__global__ __launch_bounds__(256) void ginit_k(int* __restrict__ gcursor) {
    gcursor[threadIdx.x] = threadIdx.x * BUCKCAP;
}

// K0b: bucket binning into fixed-capacity regions
__global__ __launch_bounds__(256) void bin_k(const int* __restrict__ edges,
                                             int* __restrict__ gcursor,
                                             unsigned int* __restrict__ temp) {
    __shared__ int cnt[NBUCK];
    __shared__ int gb[NBUCK];
    __shared__ int off[NBUCK];
    int tid  = threadIdx.x;
    int base = blockIdx.x * TILE;
    int sv[16], dv[16], bv[16];
    cnt[tid] = 0;
    __syncthreads();
#pragma unroll
    for (int i = 0; i < 16; ++i) {
        int e = base + i * 256 + tid;
        if (e < NEDGE) {
            sv[i] = edges[e];
            dv[i] = edges[NEDGE + e];
            bv[i] = dv[i] / KNODE;
            atomicAdd(&cnt[bv[i]], 1);
        } else {
            bv[i] = -1;
        }
    }
    __syncthreads();
    if (cnt[tid] > 0) gb[tid] = atomicAdd(&gcursor[tid], cnt[tid]);
    off[tid] = 0;
    __syncthreads();
#pragma unroll
    for (int i = 0; i < 16; ++i) {
        int b = bv[i];
        if (b >= 0) {
            int p  = atomicAdd(&off[b], 1);
            int dl = dv[i] - b * KNODE;
            temp[gb[b] + p] = ((unsigned int)sv[i] << 9) | (unsigned int)dl;
        }
    }
}

// K0c: per-bucket degree histogram from binned temp
__global__ __launch_bounds__(256) void count_k(const unsigned int* __restrict__ temp,
                                               const int* __restrict__ gcursor,
                                               int* __restrict__ degi) {
    __shared__ int cnt[KNODE];
    int b     = blockIdx.x;
    int node0 = b * KNODE;
    int nn    = N_ENT - node0; if (nn > KNODE) nn = KNODE;
    for (int i = threadIdx.x; i < KNODE; i += 256) cnt[i] = 0;
    __syncthreads();
    int tbeg = b * BUCKCAP;
    int tend = gcursor[b];
    for (int idx = tbeg + threadIdx.x; idx < tend; idx += 256)
        atomicAdd(&cnt[temp[idx] & 511u], 1);
    __syncthreads();
    for (int i = threadIdx.x; i < nn; i += 256) degi[node0 + i] = cnt[i];
}

// K3a/b/c: hierarchical exclusive scan of degi -> row_start
__global__ __launch_bounds__(256) void scan_partials(const int* __restrict__ degi,
                                                     int* __restrict__ partials) {
    __shared__ int ws[4];
    int i = blockIdx.x * 256 + threadIdx.x;
    int v = (i < N_ENT) ? degi[i] : 0;
#pragma unroll
    for (int o = 32; o > 0; o >>= 1) v += __shfl_xor(v, o, 64);
    if ((threadIdx.x & 63) == 0) ws[threadIdx.x >> 6] = v;
    __syncthreads();
    if (threadIdx.x == 0) partials[blockIdx.x] = ws[0] + ws[1] + ws[2] + ws[3];
}

__global__ __launch_bounds__(512) void scan_offsets(int* __restrict__ partials,
                                                    int* __restrict__ row_start) {
    __shared__ int ts[512];
    int t = threadIdx.x;
    int v = (t < NBLK_SCAN) ? partials[t] : 0;
    ts[t] = v;
    __syncthreads();
    for (int off = 1; off < 512; off <<= 1) {
        int x = (t >= off) ? ts[t - off] : 0;
        __syncthreads();
        ts[t] += x;
        __syncthreads();
    }
    if (t < NBLK_SCAN) partials[t] = ts[t] - v;
    if (t == 0) row_start[N_ENT] = NEDGE;
}

__global__ __launch_bounds__(256) void scan_apply(const int* __restrict__ degi,
                                                  const int* __restrict__ partials,
                                                  int* __restrict__ row_start) {
    __shared__ int ts[256];
    int t = threadIdx.x;
    int i = blockIdx.x * 256 + t;
    int v = (i < N_ENT) ? degi[i] : 0;
    ts[t] = v;
    __syncthreads();
    for (int off = 1; off < 256; off <<= 1) {
        int x = (t >= off) ? ts[t - off] : 0;
        __syncthreads();
        ts[t] += x;
        __syncthreads();
    }
    if (i < N_ENT) row_start[i] = ts[t] - v + partials[blockIdx.x];
}

// K4b: within-bucket placement
__global__ __launch_bounds__(256) void unbin_k(const unsigned int* __restrict__ temp,
                                               const int* __restrict__ gcursor,
                                               const int* __restrict__ row_start,
                                               int* __restrict__ srcs) {
    __shared__ int cur[KNODE];
    int b     = blockIdx.x;
    int node0 = b * KNODE;
    int nn    = N_ENT - node0; if (nn > KNODE) nn = KNODE;
    for (int i = threadIdx.x; i < nn; i += 256) cur[i] = row_start[node0 + i];
    __syncthreads();
    int tbeg = b * BUCKCAP;
    int tend = gcursor[b];
    for (int idx = tbeg + threadIdx.x; idx < tend; idx += 256) {
        unsigned int v = temp[idx];
        int dl = (int)(v & 511u);
        int s  = (int)(v >> 9);
        int pos = atomicAdd(&cur[dl], 1);
        srcs[pos] = s;
    }
}

// K5: layer-1 aggregate [R11 version], 4 edges per gather instruction.
__global__ __launch_bounds__(256) void reduce1_k(const int* __restrict__ row_start,
                                                 const int* __restrict__ srcs,
                                                 const unsigned short* __restrict__ emb_b,
                                                 const float* __restrict__ dinv,
                                                 float* __restrict__ z) {
    int gt   = blockIdx.x * 256 + threadIdx.x;
    int dst  = gt >> 6;
    int lane = threadIdx.x & 63;
    int sub  = lane >> 4;
    int li   = lane & 15;
    int beg = row_start[dst];
    int end = row_start[dst + 1];
    float4 acc = make_float4(0.f, 0.f, 0.f, 0.f);
    for (int base = beg; base < end; base += 64) {
        int cnt = end - base; if (cnt > 64) cnt = 64;
        int s_v = (base + lane < end) ? srcs[base + lane] : N_ENT;
        for (int jj = 0; jj < cnt; jj += 16) {
            int s0 = __shfl(s_v, jj + sub,      64);
            int s1 = __shfl(s_v, jj + 4 + sub,  64);
            int s2 = __shfl(s_v, jj + 8 + sub,  64);
            int s3 = __shfl(s_v, jj + 12 + sub, 64);
            uint2 p0 = *(const uint2*)(emb_b + (size_t)s0 * 64 + li * 4);
            uint2 p1 = *(const uint2*)(emb_b + (size_t)s1 * 64 + li * 4);
            uint2 p2 = *(const uint2*)(emb_b + (size_t)s2 * 64 + li * 4);
            uint2 p3 = *(const uint2*)(emb_b + (size_t)s3 * 64 + li * 4);
            acc.x += blo(p0.x) + blo(p1.x) + blo(p2.x) + blo(p3.x);
            acc.y += bhi(p0.x) + bhi(p1.x) + bhi(p2.x) + bhi(p3.x);
            acc.z += blo(p0.y) + blo(p1.y) + blo(p2.y) + blo(p3.y);
            acc.w += bhi(p0.y) + bhi(p1.y) + bhi(p2.y) + bhi(p3.y);
        }
    }
    acc.x += __shfl_xor(acc.x, 16, 64); acc.y += __shfl_xor(acc.y, 16, 64);
    acc.z += __shfl_xor(acc.z, 16, 64); acc.w += __shfl_xor(acc.w, 16, 64);
    acc.x += __shfl_xor(acc.x, 32, 64); acc.y += __shfl_xor(acc.y, 32, 64);
    acc.z += __shfl_xor(acc.z, 32, 64); acc.w += __shfl_xor(acc.w, 32, 64);
    if (lane < 16) {
        uint2 po = *(const uint2*)(emb_b + (size_t)dst * 64 + li * 4);
        float dv = dinv[dst];
        float4 o;
        o.x = dv * (acc.x + blo(po.x));
        o.y = dv * (acc.y + bhi(po.x));
        o.z = dv * (acc.z + blo(po.y));
        o.w = dv * (acc.w + bhi(po.y));
        *(float4*)(z + (size_t)dst * 64 + li * 4) = o;
    }
}

// K6: FUSED MLP: h2b = bf16(dinv * (relu(z@W1+b1) @ W2)) per 64-row tile.
// y1 tile lives in LDS (no y1r global round-trip). LDS = 117 KB of the
// 160 KB/CU budget -> 1 block/CU; math is the two proven register-blocked
// GEMM bodies verbatim, only the y1 store/load target changed.
__global__ __launch_bounds__(256) void gemm12_k(const float* __restrict__ z,
                                                const float* __restrict__ W1g,
                                                const float* __restrict__ b1,
                                                const float* __restrict__ W2g,
                                                const float* __restrict__ dinv,
                                                unsigned short* __restrict__ h2b) {
    __shared__ float As [64 * 68];    // z tile       (stride 17 float4)
    __shared__ float Ws1[64 * 132];   // W1           (stride 33 float4)
    __shared__ float Ws2[128 * 68];   // W2           (stride 17 float4)
    __shared__ float Ys [64 * 132];   // y1=relu tile (stride 33 float4)
    int tid  = threadIdx.x;
    int row0 = blockIdx.x * 64;
    // stage z tile (64x64)
    for (int idx = tid; idx < 1024; idx += 256) {
        int r = idx >> 4, c4 = (idx & 15) * 4;
        int grow = row0 + r;
        float4 v = make_float4(0.f, 0.f, 0.f, 0.f);
        if (grow < N_ENT) v = *(const float4*)(z + (size_t)grow * 64 + c4);
        *(float4*)(As + r * 68 + c4) = v;
    }
    // stage W1 (64x128)
    for (int idx = tid; idx < 2048; idx += 256) {
        int k = idx >> 5, c4 = (idx & 31) * 4;
        *(float4*)(Ws1 + k * 132 + c4) = *(const float4*)(W1g + k * 128 + c4);
    }
    // stage W2 (128x64)
    for (int idx = tid; idx < 2048; idx += 256) {
        int k = idx >> 4, c4 = (idx & 15) * 4;
        *(float4*)(Ws2 + k * 68 + c4) = *(const float4*)(W2g + k * 64 + c4);
    }
    __syncthreads();

    // ---- GEMM1: Ys = relu(As @ W1 + b1), 8x4 per thread ----
    {
        int cg = tid & 31;
        int rg = tid >> 5;
        int c0 = cg * 4;
        int r0 = rg * 8;
        const float4* A4 = (const float4*)As;    // row stride 17
        const float4* W4 = (const float4*)Ws1;   // row stride 33
        float acc[8][4];
#pragma unroll
        for (int i = 0; i < 8; ++i)
#pragma unroll
            for (int j = 0; j < 4; ++j) acc[i][j] = 0.f;
        for (int k4 = 0; k4 < 16; ++k4) {
            float4 w0 = W4[(4 * k4 + 0) * 33 + cg];
            float4 w1 = W4[(4 * k4 + 1) * 33 + cg];
            float4 w2 = W4[(4 * k4 + 2) * 33 + cg];
            float4 w3 = W4[(4 * k4 + 3) * 33 + cg];
#pragma unroll
            for (int i = 0; i < 8; ++i) {
                float4 a = A4[(r0 + i) * 17 + k4];
                acc[i][0] += a.x * w0.x + a.y * w1.x + a.z * w2.x + a.w * w3.x;
                acc[i][1] += a.x * w0.y + a.y * w1.y + a.z * w2.y + a.w * w3.y;
                acc[i][2] += a.x * w0.z + a.y * w1.z + a.z * w2.z + a.w * w3.z;
                acc[i][3] += a.x * w0.w + a.y * w1.w + a.z * w2.w + a.w * w3.w;
            }
        }
        float4 bb = *(const float4*)(b1 + c0);
#pragma unroll
        for (int i = 0; i < 8; ++i) {
            float4 o;
            o.x = fmaxf(acc[i][0] + bb.x, 0.f);
            o.y = fmaxf(acc[i][1] + bb.y, 0.f);
            o.z = fmaxf(acc[i][2] + bb.z, 0.f);
            o.w = fmaxf(acc[i][3] + bb.w, 0.f);
            *(float4*)(Ys + (r0 + i) * 132 + c0) = o;
        }
    }
    __syncthreads();

    // ---- GEMM2: h2b = bf16(dinv * (Ys @ W2)), 4x4 per thread ----
    {
        int cg = tid & 15;
        int rg = tid >> 4;
        int c0 = cg * 4;
        int r0 = rg * 4;
        const float4* Y4 = (const float4*)Ys;    // row stride 33
        const float4* W4 = (const float4*)Ws2;   // row stride 17
        float acc[4][4];
#pragma unroll
        for (int i = 0; i < 4; ++i)
#pragma unroll
            for (int j = 0; j < 4; ++j) acc[i][j] = 0.f;
        for (int k4 = 0; k4 < 32; ++k4) {
            float4 w0 = W4[(4 * k4 + 0) * 17 + cg];
            float4 w1 = W4[(4 * k4 + 1) * 17 + cg];
            float4 w2 = W4[(4 * k4 + 2) * 17 + cg];
            float4 w3 = W4[(4 * k4 + 3) * 17 + cg];
#pragma unroll
            for (int i = 0; i < 4; ++i) {
                float4 a = Y4[(r0 + i) * 33 + k4];
                acc[i][0] += a.x * w0.x + a.y * w1.x + a.z * w2.x + a.w * w3.x;
                acc[i][1] += a.x * w0.y + a.y * w1.y + a.z * w2.y + a.w * w3.y;
                acc[i][2] += a.x * w0.z + a.y * w1.z + a.z * w2.z + a.w * w3.z;
                acc[i][3] += a.x * w0.w + a.y * w1.w + a.z * w2.w + a.w * w3.w;
            }
        }
#pragma unroll
        for (int i = 0; i < 4; ++i) {
            int grow = row0 + r0 + i;
            if (grow < N_ENT) {
                float dv = dinv[grow];
                unsigned int h0 = f2b(acc[i][0] * dv);
                unsigned int h1 = f2b(acc[i][1] * dv);
                unsigned int h2 = f2b(acc[i][2] * dv);
                unsigned int h3 = f2b(acc[i][3] * dv);
                uint2 p;
                p.x = h0 | (h1 << 16);
                p.y = h2 | (h3 << 16);
                *(uint2*)(h2b + (size_t)grow * 64 + c0) = p;
            } else if (grow == N_ENT) {
                uint2 p; p.x = 0u; p.y = 0u;
                *(uint2*)(h2b + (size_t)grow * 64 + c0) = p;
            }
        }
    }
}

// K8: fused layer-2 aggregate + final dot for the 8192 batch items.
__global__ __launch_bounds__(256) void reduce2f_k(const int* __restrict__ u,
                                                  const int* __restrict__ iidx,
                                                  const float* __restrict__ uemb,
                                                  const int* __restrict__ row_start,
                                                  const int* __restrict__ srcs,
                                                  const unsigned short* __restrict__ h2b,
                                                  const float* __restrict__ dinv,
                                                  const float* __restrict__ b2,
                                                  float* __restrict__ out) {
    int gt   = blockIdx.x * 256 + threadIdx.x;
    int b    = gt >> 6;
    int lane = threadIdx.x & 63;
    int sub  = lane >> 4;
    int li   = lane & 15;
    int dst = iidx[b];
    int beg = row_start[dst];
    int end = row_start[dst + 1];
    float4 acc = make_float4(0.f, 0.f, 0.f, 0.f);
    for (int base = beg; base < end; base += 64) {
        int cnt = end - base; if (cnt > 64) cnt = 64;
        int s_v = (base + lane < end) ? srcs[base + lane] : N_ENT;
        for (int jj = 0; jj < cnt; jj += 16) {
            int s0 = __shfl(s_v, jj + sub,      64);
            int s1 = __shfl(s_v, jj + 4 + sub,  64);
            int s2 = __shfl(s_v, jj + 8 + sub,  64);
            int s3 = __shfl(s_v, jj + 12 + sub, 64);
            uint2 p0 = *(const uint2*)(h2b + (size_t)s0 * 64 + li * 4);
            uint2 p1 = *(const uint2*)(h2b + (size_t)s1 * 64 + li * 4);
            uint2 p2 = *(const uint2*)(h2b + (size_t)s2 * 64 + li * 4);
            uint2 p3 = *(const uint2*)(h2b + (size_t)s3 * 64 + li * 4);
            acc.x += blo(p0.x) + blo(p1.x) + blo(p2.x) + blo(p3.x);
            acc.y += bhi(p0.x) + bhi(p1.x) + bhi(p2.x) + bhi(p3.x);
            acc.z += blo(p0.y) + blo(p1.y) + blo(p2.y) + blo(p3.y);
            acc.w += bhi(p0.y) + bhi(p1.y) + bhi(p2.y) + bhi(p3.y);
        }
    }
    acc.x += __shfl_xor(acc.x, 16, 64); acc.y += __shfl_xor(acc.y, 16, 64);
    acc.z += __shfl_xor(acc.z, 16, 64); acc.w += __shfl_xor(acc.w, 16, 64);
    acc.x += __shfl_xor(acc.x, 32, 64); acc.y += __shfl_xor(acc.y, 32, 64);
    acc.z += __shfl_xor(acc.z, 32, 64); acc.w += __shfl_xor(acc.w, 32, 64);
    float s1 = 0.f, s2 = 0.f;
    if (lane < 16) {
        uint2 po = *(const uint2*)(h2b + (size_t)dst * 64 + li * 4);
        float dv = dinv[dst];
        float4 bb = *(const float4*)(b2 + li * 4);
        float4 z2v;
        z2v.x = dv * (acc.x + blo(po.x)) + bb.x;
        z2v.y = dv * (acc.y + bhi(po.x)) + bb.y;
        z2v.z = dv * (acc.z + blo(po.y)) + bb.z;
        z2v.w = dv * (acc.w + bhi(po.y)) + bb.w;
        float4 ue = *(const float4*)(uemb + (size_t)u[b] * 64 + li * 4);
        s1 = ue.x * ue.x + ue.y * ue.y + ue.z * ue.z + ue.w * ue.w;
        s2 = ue.x * z2v.x + ue.y * z2v.y + ue.z * z2v.z + ue.w * z2v.w;
    }
#pragma unroll
    for (int o = 8; o > 0; o >>= 1) {
        s1 += __shfl_xor(s1, o, 64);
        s2 += __shfl_xor(s2, o, 64);
    }
    if (lane == 0) {
        float nrm = sqrtf(s1);
        float sc  = nrm > 1.0f ? 1.0f / nrm : 1.0f;
        float uv  = s2 * sc;
        out[b] = 1.0f / (1.0f + expf(-uv));
    }
}

// ---------------------------------------------------------------------------
extern "C" void kernel_launch(void* const* d_in, const int* in_sizes, int n_in,
                              void* d_out, int out_size, void* d_ws, size_t ws_size,
                              hipStream_t stream) {
    const int*   u          = (const int*)d_in[0];
    const int*   iidx       = (const int*)d_in[1];
    const int*   edges      = (const int*)d_in[2];
    const float* user_emb   = (const float*)d_in[3];
    const float* entity_emb = (const float*)d_in[4];
    const float* W1         = (const float*)d_in[5];
    const float* b1         = (const float*)d_in[6];
    const float* W2         = (const float*)d_in[7];
    const float* b2         = (const float*)d_in[8];
    float*       out        = (float*)d_out;

    char* ws = (char*)d_ws;
    int*            degi      = (int*)           (ws);
    float*          dinv      = (float*)         (ws + 100000u * 4);
    int*            row_start = (int*)           (ws + 200000u * 4);
    int*            gcursor   = (int*)           (ws + 300004u * 4);
    int*            partials  = (int*)           (ws + 300264u * 4);
    int*            srcs      = (int*)           (ws + 300656u * 4);
    unsigned short* emb_b     = (unsigned short*)(ws + 1900656u * 4);  // (N+1)*64
    float*          z         = (float*)         (ws + 5100688u * 4);
    unsigned int*   temp      = (unsigned int*)  (ws + 11500688u * 4); // dead before gemm12
    unsigned short* h2b       = (unsigned short*)z;    // z dead after gemm12 reads it... see below

    // NOTE: gemm12 reads z tile-by-tile and writes h2b over the same region.
    // h2b[grow] (bf16, 128 B/row) overwrites z[grow] (f32, 256 B/row) — but a
    // block writes rows it has ALREADY staged into LDS, and h2b row g occupies
    // the first half of z row g's bytes only for g in the same tile... To be
    // safe against cross-tile aliasing (h2b row 2g+1 lands in z row g's
    // second half AFTER z row g was read only if dispatch order is adverse),
    // place h2b in the temp region instead (temp is dead by gemm12 time).
    h2b = (unsigned short*)temp;

    ginit_k<<<1, 256, 0, stream>>>(gcursor);
    bin_k<<<NTILE, 256, 0, stream>>>(edges, gcursor, temp);
    count_k<<<NBUCK, 256, 0, stream>>>(temp, gcursor, degi);

    prep_k<<<N_ENT * 64 / 256 + 1, 256, 0, stream>>>(entity_emb, degi, dinv, emb_b);

    scan_partials<<<NBLK_SCAN, 256, 0, stream>>>(degi, partials);
    scan_offsets<<<1, 512, 0, stream>>>(partials, row_start);
    scan_apply<<<NBLK_SCAN, 256, 0, stream>>>(degi, partials, row_start);

    unbin_k<<<NBUCK, 256, 0, stream>>>(temp, gcursor, row_start, srcs);

    reduce1_k<<<N_ENT * 64 / 256, 256, 0, stream>>>(row_start, srcs, emb_b, dinv, z);
    gemm12_k<<<NBLK_G, 256, 0, stream>>>(z, W1, b1, W2, dinv, h2b);

    reduce2f_k<<<BATCH * 64 / 256, 256, 0, stream>>>(u, iidx, user_emb, row_start,
                                                     srcs, h2b, dinv, b2, out);
}

// Round 14
// 305.033 us; speedup vs baseline: 1.1748x; 1.0657x over previous
//
#include <hip/hip_runtime.h>
#include <hip/hip_bf16.h>
#include <math.h>

// Problem constants (from reference)
constexpr int N_ENT = 100000;
constexpr int NEDGE = 1600000;
constexpr int BATCH = 8192;
constexpr int NBLK_SCAN = (N_ENT + 255) / 256;   // 391

// Bucketed CSR placement
constexpr int NBUCK   = 256;
constexpr int KNODE   = 391;                      // 256*391 >= N_ENT
constexpr int TILE    = 4096;
constexpr int NTILE   = (NEDGE + TILE - 1) / TILE; // 391
constexpr int BUCKCAP = 8192;                     // fixed bucket region

constexpr int NBLK_G = (N_ENT + 63) / 64;         // 1563 (64-row GEMM tiles)

// bf16 helpers (RNE pack, exact unpack)
__device__ inline unsigned short f2b(float x) {
    unsigned int u = __float_as_uint(x);
    unsigned int r = (u + 0x7fffu + ((u >> 16) & 1u)) >> 16;
    return (unsigned short)r;
}
__device__ inline float b2f(unsigned short h) {
    return __uint_as_float(((unsigned int)h) << 16);
}
__device__ inline float blo(unsigned int p) { return __uint_as_float(p << 16); }
__device__ inline float bhi(unsigned int p) { return __uint_as_float(p & 0xffff0000u); }

// ---------------------------------------------------------------------------
// Workspace layout (4-byte units):
//  degi      : [0, 100000)
//  dinv      : [100000, 200000)
//  row_start : [200000, 300001)
//  gcursor   : [300004, 300260)
//  partials  : [300264, 300655)
//  srcs      : [300656, 1900656)
//  emb_b     : [1900656, 5100688)   ushort[(N+1)*64] (+ zero row)
//  z / h2b   : [5100688, 11500688)  float [N,64]; h2b (ushort[(N+1)*64]) reuses
//                                   (safe: gemm2 never reads z)
//  temp/y1b  : [11500688, 17900688) uint temp (dead after unbin) then
//                                   y1b ushort[N*128] (bf16 intermediate)

// K1: prep — dinv + premultiplied bf16 entity rows (+ zero row at N_ENT)
__global__ __launch_bounds__(256) void prep_k(const float* __restrict__ emb,
                                              const int* __restrict__ degi,
                                              float* __restrict__ dinv,
                                              unsigned short* __restrict__ emb_b) {
    int gt   = blockIdx.x * 256 + threadIdx.x;
    int n    = gt >> 6;
    int lane = threadIdx.x & 63;
    if (n > N_ENT) return;
    if (n == N_ENT) { emb_b[(size_t)n * 64 + lane] = 0; return; }
    float v = emb[(size_t)n * 64 + lane];
    float s = v * v;
#pragma unroll
    for (int o = 32; o > 0; o >>= 1) s += __shfl_xor(s, o, 64);
    float nrm = sqrtf(s);
    float sc  = nrm > 1.0f ? 1.0f / nrm : 1.0f;
    float dv  = 1.0f / sqrtf((float)(degi[n] + 1));
    if (lane == 0) dinv[n] = dv;
    emb_b[(size_t)n * 64 + lane] = f2b(sc * dv * v);
}

// K0a: gcursor init to fixed bucket bases
__global__ __launch_bounds__(256) void ginit_k(int* __restrict__ gcursor) {
    gcursor[threadIdx.x] = threadIdx.x * BUCKCAP;
}

// K0b: bucket binning into fixed-capacity regions
__global__ __launch_bounds__(256) void bin_k(const int* __restrict__ edges,
                                             int* __restrict__ gcursor,
                                             unsigned int* __restrict__ temp) {
    __shared__ int cnt[NBUCK];
    __shared__ int gb[NBUCK];
    __shared__ int off[NBUCK];
    int tid  = threadIdx.x;
    int base = blockIdx.x * TILE;
    int sv[16], dv[16], bv[16];
    cnt[tid] = 0;
    __syncthreads();
#pragma unroll
    for (int i = 0; i < 16; ++i) {
        int e = base + i * 256 + tid;
        if (e < NEDGE) {
            sv[i] = edges[e];
            dv[i] = edges[NEDGE + e];
            bv[i] = dv[i] / KNODE;
            atomicAdd(&cnt[bv[i]], 1);
        } else {
            bv[i] = -1;
        }
    }
    __syncthreads();
    if (cnt[tid] > 0) gb[tid] = atomicAdd(&gcursor[tid], cnt[tid]);
    off[tid] = 0;
    __syncthreads();
#pragma unroll
    for (int i = 0; i < 16; ++i) {
        int b = bv[i];
        if (b >= 0) {
            int p  = atomicAdd(&off[b], 1);
            int dl = dv[i] - b * KNODE;
            temp[gb[b] + p] = ((unsigned int)sv[i] << 9) | (unsigned int)dl;
        }
    }
}

// K0c: per-bucket degree histogram from binned temp
__global__ __launch_bounds__(256) void count_k(const unsigned int* __restrict__ temp,
                                               const int* __restrict__ gcursor,
                                               int* __restrict__ degi) {
    __shared__ int cnt[KNODE];
    int b     = blockIdx.x;
    int node0 = b * KNODE;
    int nn    = N_ENT - node0; if (nn > KNODE) nn = KNODE;
    for (int i = threadIdx.x; i < KNODE; i += 256) cnt[i] = 0;
    __syncthreads();
    int tbeg = b * BUCKCAP;
    int tend = gcursor[b];
    for (int idx = tbeg + threadIdx.x; idx < tend; idx += 256)
        atomicAdd(&cnt[temp[idx] & 511u], 1);
    __syncthreads();
    for (int i = threadIdx.x; i < nn; i += 256) degi[node0 + i] = cnt[i];
}

// K3a/b/c: hierarchical exclusive scan of degi -> row_start
__global__ __launch_bounds__(256) void scan_partials(const int* __restrict__ degi,
                                                     int* __restrict__ partials) {
    __shared__ int ws[4];
    int i = blockIdx.x * 256 + threadIdx.x;
    int v = (i < N_ENT) ? degi[i] : 0;
#pragma unroll
    for (int o = 32; o > 0; o >>= 1) v += __shfl_xor(v, o, 64);
    if ((threadIdx.x & 63) == 0) ws[threadIdx.x >> 6] = v;
    __syncthreads();
    if (threadIdx.x == 0) partials[blockIdx.x] = ws[0] + ws[1] + ws[2] + ws[3];
}

__global__ __launch_bounds__(512) void scan_offsets(int* __restrict__ partials,
                                                    int* __restrict__ row_start) {
    __shared__ int ts[512];
    int t = threadIdx.x;
    int v = (t < NBLK_SCAN) ? partials[t] : 0;
    ts[t] = v;
    __syncthreads();
    for (int off = 1; off < 512; off <<= 1) {
        int x = (t >= off) ? ts[t - off] : 0;
        __syncthreads();
        ts[t] += x;
        __syncthreads();
    }
    if (t < NBLK_SCAN) partials[t] = ts[t] - v;
    if (t == 0) row_start[N_ENT] = NEDGE;
}

__global__ __launch_bounds__(256) void scan_apply(const int* __restrict__ degi,
                                                  const int* __restrict__ partials,
                                                  int* __restrict__ row_start) {
    __shared__ int ts[256];
    int t = threadIdx.x;
    int i = blockIdx.x * 256 + t;
    int v = (i < N_ENT) ? degi[i] : 0;
    ts[t] = v;
    __syncthreads();
    for (int off = 1; off < 256; off <<= 1) {
        int x = (t >= off) ? ts[t - off] : 0;
        __syncthreads();
        ts[t] += x;
        __syncthreads();
    }
    if (i < N_ENT) row_start[i] = ts[t] - v + partials[blockIdx.x];
}

// K4b: within-bucket placement
__global__ __launch_bounds__(256) void unbin_k(const unsigned int* __restrict__ temp,
                                               const int* __restrict__ gcursor,
                                               const int* __restrict__ row_start,
                                               int* __restrict__ srcs) {
    __shared__ int cur[KNODE];
    int b     = blockIdx.x;
    int node0 = b * KNODE;
    int nn    = N_ENT - node0; if (nn > KNODE) nn = KNODE;
    for (int i = threadIdx.x; i < nn; i += 256) cur[i] = row_start[node0 + i];
    __syncthreads();
    int tbeg = b * BUCKCAP;
    int tend = gcursor[b];
    for (int idx = tbeg + threadIdx.x; idx < tend; idx += 256) {
        unsigned int v = temp[idx];
        int dl = (int)(v & 511u);
        int s  = (int)(v >> 9);
        int pos = atomicAdd(&cur[dl], 1);
        srcs[pos] = s;
    }
}

// K5: layer-1 aggregate [R11 version], 4 edges per gather instruction.
__global__ __launch_bounds__(256) void reduce1_k(const int* __restrict__ row_start,
                                                 const int* __restrict__ srcs,
                                                 const unsigned short* __restrict__ emb_b,
                                                 const float* __restrict__ dinv,
                                                 float* __restrict__ z) {
    int gt   = blockIdx.x * 256 + threadIdx.x;
    int dst  = gt >> 6;
    int lane = threadIdx.x & 63;
    int sub  = lane >> 4;
    int li   = lane & 15;
    int beg = row_start[dst];
    int end = row_start[dst + 1];
    float4 acc = make_float4(0.f, 0.f, 0.f, 0.f);
    for (int base = beg; base < end; base += 64) {
        int cnt = end - base; if (cnt > 64) cnt = 64;
        int s_v = (base + lane < end) ? srcs[base + lane] : N_ENT;
        for (int jj = 0; jj < cnt; jj += 16) {
            int s0 = __shfl(s_v, jj + sub,      64);
            int s1 = __shfl(s_v, jj + 4 + sub,  64);
            int s2 = __shfl(s_v, jj + 8 + sub,  64);
            int s3 = __shfl(s_v, jj + 12 + sub, 64);
            uint2 p0 = *(const uint2*)(emb_b + (size_t)s0 * 64 + li * 4);
            uint2 p1 = *(const uint2*)(emb_b + (size_t)s1 * 64 + li * 4);
            uint2 p2 = *(const uint2*)(emb_b + (size_t)s2 * 64 + li * 4);
            uint2 p3 = *(const uint2*)(emb_b + (size_t)s3 * 64 + li * 4);
            acc.x += blo(p0.x) + blo(p1.x) + blo(p2.x) + blo(p3.x);
            acc.y += bhi(p0.x) + bhi(p1.x) + bhi(p2.x) + bhi(p3.x);
            acc.z += blo(p0.y) + blo(p1.y) + blo(p2.y) + blo(p3.y);
            acc.w += bhi(p0.y) + bhi(p1.y) + bhi(p2.y) + bhi(p3.y);
        }
    }
    acc.x += __shfl_xor(acc.x, 16, 64); acc.y += __shfl_xor(acc.y, 16, 64);
    acc.z += __shfl_xor(acc.z, 16, 64); acc.w += __shfl_xor(acc.w, 16, 64);
    acc.x += __shfl_xor(acc.x, 32, 64); acc.y += __shfl_xor(acc.y, 32, 64);
    acc.z += __shfl_xor(acc.z, 32, 64); acc.w += __shfl_xor(acc.w, 32, 64);
    if (lane < 16) {
        uint2 po = *(const uint2*)(emb_b + (size_t)dst * 64 + li * 4);
        float dv = dinv[dst];
        float4 o;
        o.x = dv * (acc.x + blo(po.x));
        o.y = dv * (acc.y + bhi(po.x));
        o.z = dv * (acc.z + blo(po.y));
        o.w = dv * (acc.w + bhi(po.y));
        *(float4*)(z + (size_t)dst * 64 + li * 4) = o;
    }
}

// K6: y1b = bf16(relu(z @ W1 + b1))  [N,64]@[64,128] — register-blocked
// 8x4/thread (R11 body; only the output store packs to bf16, halving the
// 51.2 MB y1 intermediate write). [R13 lesson: GEMMs here are occupancy-
// bound, not traffic-bound — keep LDS small, two kernels]
__global__ __launch_bounds__(256) void gemm1_relu(const float* __restrict__ z,
                                                  const float* __restrict__ W1g,
                                                  const float* __restrict__ b1,
                                                  unsigned short* __restrict__ y1b) {
    __shared__ float As[64 * 68];
    __shared__ float Ws[64 * 132];
    int tid  = threadIdx.x;
    int row0 = blockIdx.x * 64;
    for (int idx = tid; idx < 1024; idx += 256) {
        int r = idx >> 4, c4 = (idx & 15) * 4;
        int grow = row0 + r;
        float4 v = make_float4(0.f, 0.f, 0.f, 0.f);
        if (grow < N_ENT) v = *(const float4*)(z + (size_t)grow * 64 + c4);
        *(float4*)(As + r * 68 + c4) = v;
    }
    for (int idx = tid; idx < 2048; idx += 256) {
        int k = idx >> 5, c4 = (idx & 31) * 4;
        *(float4*)(Ws + k * 132 + c4) = *(const float4*)(W1g + k * 128 + c4);
    }
    __syncthreads();

    int cg = tid & 31;
    int rg = tid >> 5;
    int c0 = cg * 4;
    int r0 = rg * 8;
    const float4* A4 = (const float4*)As;   // row stride 17
    const float4* W4 = (const float4*)Ws;   // row stride 33
    float acc[8][4];
#pragma unroll
    for (int i = 0; i < 8; ++i)
#pragma unroll
        for (int j = 0; j < 4; ++j) acc[i][j] = 0.f;

    for (int k4 = 0; k4 < 16; ++k4) {
        float4 w0 = W4[(4 * k4 + 0) * 33 + cg];
        float4 w1 = W4[(4 * k4 + 1) * 33 + cg];
        float4 w2 = W4[(4 * k4 + 2) * 33 + cg];
        float4 w3 = W4[(4 * k4 + 3) * 33 + cg];
#pragma unroll
        for (int i = 0; i < 8; ++i) {
            float4 a = A4[(r0 + i) * 17 + k4];
            acc[i][0] += a.x * w0.x + a.y * w1.x + a.z * w2.x + a.w * w3.x;
            acc[i][1] += a.x * w0.y + a.y * w1.y + a.z * w2.y + a.w * w3.y;
            acc[i][2] += a.x * w0.z + a.y * w1.z + a.z * w2.z + a.w * w3.z;
            acc[i][3] += a.x * w0.w + a.y * w1.w + a.z * w2.w + a.w * w3.w;
        }
    }
    float4 bb = *(const float4*)(b1 + c0);
#pragma unroll
    for (int i = 0; i < 8; ++i) {
        int grow = row0 + r0 + i;
        if (grow < N_ENT) {
            unsigned int h0 = f2b(fmaxf(acc[i][0] + bb.x, 0.f));
            unsigned int h1 = f2b(fmaxf(acc[i][1] + bb.y, 0.f));
            unsigned int h2 = f2b(fmaxf(acc[i][2] + bb.z, 0.f));
            unsigned int h3 = f2b(fmaxf(acc[i][3] + bb.w, 0.f));
            uint2 p;
            p.x = h0 | (h1 << 16);
            p.y = h2 | (h3 << 16);
            *(uint2*)(y1b + (size_t)grow * 128 + c0) = p;
        }
    }
}

// K7: h2b = bf16(dinv[row]*(y1b @ W2))  [N,128]@[128,64] — 4x4/thread.
// y1b unpacked bf16->f32 during LDS staging; inner loop identical to R11
// (conflict-free ds_read_b128). Also writes zero row at N_ENT.
__global__ __launch_bounds__(256) void gemm2_k(const unsigned short* __restrict__ y1b,
                                               const float* __restrict__ W2g,
                                               const float* __restrict__ dinv,
                                               unsigned short* __restrict__ h2b) {
    __shared__ float Ys[64 * 132];
    __shared__ float Ws[128 * 68];
    int tid  = threadIdx.x;
    int row0 = blockIdx.x * 64;
    for (int idx = tid; idx < 2048; idx += 256) {
        int r = idx >> 5, c4 = (idx & 31) * 4;
        int grow = row0 + r;
        uint2 p = make_uint2(0u, 0u);
        if (grow < N_ENT) p = *(const uint2*)(y1b + (size_t)grow * 128 + c4);
        float4 v;
        v.x = blo(p.x); v.y = bhi(p.x); v.z = blo(p.y); v.w = bhi(p.y);
        *(float4*)(Ys + r * 132 + c4) = v;
    }
    for (int idx = tid; idx < 2048; idx += 256) {
        int k = idx >> 4, c4 = (idx & 15) * 4;
        *(float4*)(Ws + k * 68 + c4) = *(const float4*)(W2g + k * 64 + c4);
    }
    __syncthreads();

    int cg = tid & 15;
    int rg = tid >> 4;
    int c0 = cg * 4;
    int r0 = rg * 4;
    const float4* Y4 = (const float4*)Ys;   // row stride 33
    const float4* W4 = (const float4*)Ws;   // row stride 17
    float acc[4][4];
#pragma unroll
    for (int i = 0; i < 4; ++i)
#pragma unroll
        for (int j = 0; j < 4; ++j) acc[i][j] = 0.f;

    for (int k4 = 0; k4 < 32; ++k4) {
        float4 w0 = W4[(4 * k4 + 0) * 17 + cg];
        float4 w1 = W4[(4 * k4 + 1) * 17 + cg];
        float4 w2 = W4[(4 * k4 + 2) * 17 + cg];
        float4 w3 = W4[(4 * k4 + 3) * 17 + cg];
#pragma unroll
        for (int i = 0; i < 4; ++i) {
            float4 a = Y4[(r0 + i) * 33 + k4];
            acc[i][0] += a.x * w0.x + a.y * w1.x + a.z * w2.x + a.w * w3.x;
            acc[i][1] += a.x * w0.y + a.y * w1.y + a.z * w2.y + a.w * w3.y;
            acc[i][2] += a.x * w0.z + a.y * w1.z + a.z * w2.z + a.w * w3.z;
            acc[i][3] += a.x * w0.w + a.y * w1.w + a.z * w2.w + a.w * w3.w;
        }
    }
#pragma unroll
    for (int i = 0; i < 4; ++i) {
        int grow = row0 + r0 + i;
        if (grow < N_ENT) {
            float dv = dinv[grow];
            unsigned int h0 = f2b(acc[i][0] * dv);
            unsigned int h1 = f2b(acc[i][1] * dv);
            unsigned int h2 = f2b(acc[i][2] * dv);
            unsigned int h3 = f2b(acc[i][3] * dv);
            uint2 p;
            p.x = h0 | (h1 << 16);
            p.y = h2 | (h3 << 16);
            *(uint2*)(h2b + (size_t)grow * 64 + c0) = p;
        } else if (grow == N_ENT) {
            uint2 p; p.x = 0u; p.y = 0u;
            *(uint2*)(h2b + (size_t)grow * 64 + c0) = p;
        }
    }
}

// K8: fused layer-2 aggregate + final dot for the 8192 batch items.
__global__ __launch_bounds__(256) void reduce2f_k(const int* __restrict__ u,
                                                  const int* __restrict__ iidx,
                                                  const float* __restrict__ uemb,
                                                  const int* __restrict__ row_start,
                                                  const int* __restrict__ srcs,
                                                  const unsigned short* __restrict__ h2b,
                                                  const float* __restrict__ dinv,
                                                  const float* __restrict__ b2,
                                                  float* __restrict__ out) {
    int gt   = blockIdx.x * 256 + threadIdx.x;
    int b    = gt >> 6;
    int lane = threadIdx.x & 63;
    int sub  = lane >> 4;
    int li   = lane & 15;
    int dst = iidx[b];
    int beg = row_start[dst];
    int end = row_start[dst + 1];
    float4 acc = make_float4(0.f, 0.f, 0.f, 0.f);
    for (int base = beg; base < end; base += 64) {
        int cnt = end - base; if (cnt > 64) cnt = 64;
        int s_v = (base + lane < end) ? srcs[base + lane] : N_ENT;
        for (int jj = 0; jj < cnt; jj += 16) {
            int s0 = __shfl(s_v, jj + sub,      64);
            int s1 = __shfl(s_v, jj + 4 + sub,  64);
            int s2 = __shfl(s_v, jj + 8 + sub,  64);
            int s3 = __shfl(s_v, jj + 12 + sub, 64);
            uint2 p0 = *(const uint2*)(h2b + (size_t)s0 * 64 + li * 4);
            uint2 p1 = *(const uint2*)(h2b + (size_t)s1 * 64 + li * 4);
            uint2 p2 = *(const uint2*)(h2b + (size_t)s2 * 64 + li * 4);
            uint2 p3 = *(const uint2*)(h2b + (size_t)s3 * 64 + li * 4);
            acc.x += blo(p0.x) + blo(p1.x) + blo(p2.x) + blo(p3.x);
            acc.y += bhi(p0.x) + bhi(p1.x) + bhi(p2.x) + bhi(p3.x);
            acc.z += blo(p0.y) + blo(p1.y) + blo(p2.y) + blo(p3.y);
            acc.w += bhi(p0.y) + bhi(p1.y) + bhi(p2.y) + bhi(p3.y);
        }
    }
    acc.x += __shfl_xor(acc.x, 16, 64); acc.y += __shfl_xor(acc.y, 16, 64);
    acc.z += __shfl_xor(acc.z, 16, 64); acc.w += __shfl_xor(acc.w, 16, 64);
    acc.x += __shfl_xor(acc.x, 32, 64); acc.y += __shfl_xor(acc.y, 32, 64);
    acc.z += __shfl_xor(acc.z, 32, 64); acc.w += __shfl_xor(acc.w, 32, 64);
    float s1 = 0.f, s2 = 0.f;
    if (lane < 16) {
        uint2 po = *(const uint2*)(h2b + (size_t)dst * 64 + li * 4);
        float dv = dinv[dst];
        float4 bb = *(const float4*)(b2 + li * 4);
        float4 z2v;
        z2v.x = dv * (acc.x + blo(po.x)) + bb.x;
        z2v.y = dv * (acc.y + bhi(po.x)) + bb.y;
        z2v.z = dv * (acc.z + blo(po.y)) + bb.z;
        z2v.w = dv * (acc.w + bhi(po.y)) + bb.w;
        float4 ue = *(const float4*)(uemb + (size_t)u[b] * 64 + li * 4);
        s1 = ue.x * ue.x + ue.y * ue.y + ue.z * ue.z + ue.w * ue.w;
        s2 = ue.x * z2v.x + ue.y * z2v.y + ue.z * z2v.z + ue.w * z2v.w;
    }
#pragma unroll
    for (int o = 8; o > 0; o >>= 1) {
        s1 += __shfl_xor(s1, o, 64);
        s2 += __shfl_xor(s2, o, 64);
    }
    if (lane == 0) {
        float nrm = sqrtf(s1);
        float sc  = nrm > 1.0f ? 1.0f / nrm : 1.0f;
        float uv  = s2 * sc;
        out[b] = 1.0f / (1.0f + expf(-uv));
    }
}

// ---------------------------------------------------------------------------
extern "C" void kernel_launch(void* const* d_in, const int* in_sizes, int n_in,
                              void* d_out, int out_size, void* d_ws, size_t ws_size,
                              hipStream_t stream) {
    const int*   u          = (const int*)d_in[0];
    const int*   iidx       = (const int*)d_in[1];
    const int*   edges      = (const int*)d_in[2];
    const float* user_emb   = (const float*)d_in[3];
    const float* entity_emb = (const float*)d_in[4];
    const float* W1         = (const float*)d_in[5];
    const float* b1         = (const float*)d_in[6];
    const float* W2         = (const float*)d_in[7];
    const float* b2         = (const float*)d_in[8];
    float*       out        = (float*)d_out;

    char* ws = (char*)d_ws;
    int*            degi      = (int*)           (ws);
    float*          dinv      = (float*)         (ws + 100000u * 4);
    int*            row_start = (int*)           (ws + 200000u * 4);
    int*            gcursor   = (int*)           (ws + 300004u * 4);
    int*            partials  = (int*)           (ws + 300264u * 4);
    int*            srcs      = (int*)           (ws + 300656u * 4);
    unsigned short* emb_b     = (unsigned short*)(ws + 1900656u * 4);  // (N+1)*64
    float*          z         = (float*)         (ws + 5100688u * 4);
    unsigned int*   temp      = (unsigned int*)  (ws + 11500688u * 4); // dead after unbin
    unsigned short* y1b       = (unsigned short*)temp;  // overlays temp after unbin
    unsigned short* h2b       = (unsigned short*)z;     // overlays z (gemm2 reads only y1b)

    ginit_k<<<1, 256, 0, stream>>>(gcursor);
    bin_k<<<NTILE, 256, 0, stream>>>(edges, gcursor, temp);
    count_k<<<NBUCK, 256, 0, stream>>>(temp, gcursor, degi);

    prep_k<<<N_ENT * 64 / 256 + 1, 256, 0, stream>>>(entity_emb, degi, dinv, emb_b);

    scan_partials<<<NBLK_SCAN, 256, 0, stream>>>(degi, partials);
    scan_offsets<<<1, 512, 0, stream>>>(partials, row_start);
    scan_apply<<<NBLK_SCAN, 256, 0, stream>>>(degi, partials, row_start);

    unbin_k<<<NBUCK, 256, 0, stream>>>(temp, gcursor, row_start, srcs);

    reduce1_k<<<N_ENT * 64 / 256, 256, 0, stream>>>(row_start, srcs, emb_b, dinv, z);
    gemm1_relu<<<NBLK_G, 256, 0, stream>>>(z, W1, b1, y1b);
    gemm2_k<<<NBLK_G, 256, 0, stream>>>(y1b, W2, dinv, h2b);

    reduce2f_k<<<BATCH * 64 / 256, 256, 0, stream>>>(u, iidx, user_emb, row_start,
                                                     srcs, h2b, dinv, b2, out);
}

// Round 15
// 241.945 us; speedup vs baseline: 1.4812x; 1.2608x over previous
//
#include <hip/hip_runtime.h>
#include <hip/hip_bf16.h>
#include <math.h>

// Problem constants (from reference)
constexpr int N_ENT = 100000;
constexpr int NEDGE = 1600000;
constexpr int BATCH = 8192;
constexpr int NBLK_SCAN = (N_ENT + 255) / 256;   // 391

// Bucketed CSR placement
constexpr int NBUCK   = 256;
constexpr int KNODE   = 391;                      // 256*391 >= N_ENT
constexpr int TILE    = 4096;
constexpr int NTILE   = (NEDGE + TILE - 1) / TILE; // 391
constexpr int BUCKCAP = 8192;                     // fixed bucket region

constexpr int NBLK_G = (N_ENT + 63) / 64;         // 1563 (64-row MLP tiles)
constexpr int ZROWS  = NBLK_G * 64;               // 100032 <= padded zb rows

// MFMA fragment types (gfx950; 8 bf16 = 4 VGPRs, 4 f32 acc)
typedef __attribute__((ext_vector_type(8))) short bf16x8;
typedef __attribute__((ext_vector_type(4))) float f32x4;

// bf16 helpers (RNE pack, exact unpack)
__device__ inline unsigned short f2b(float x) {
    unsigned int u = __float_as_uint(x);
    unsigned int r = (u + 0x7fffu + ((u >> 16) & 1u)) >> 16;
    return (unsigned short)r;
}
__device__ inline float b2f(unsigned short h) {
    return __uint_as_float(((unsigned int)h) << 16);
}
__device__ inline float blo(unsigned int p) { return __uint_as_float(p << 16); }
__device__ inline float bhi(unsigned int p) { return __uint_as_float(p & 0xffff0000u); }

// ---------------------------------------------------------------------------
// Workspace layout (4-byte units):
//  degi      : [0, 100000)
//  dinv      : [100000, 200000)
//  row_start : [200000, 300001)
//  gcursor   : [300004, 300260)
//  partials  : [300264, 300655)
//  w1p       : [300656, 304752)    uint4[1024] packed W1 B-frags (bf16)
//  w2p       : [304752, 308848)    uint4[1024] packed W2 B-frags (bf16)
//  srcs      : [308848, 1908848)
//  emb_b     : [1908848, 3508864)  ushort[(N+1)*64]
//  zb        : [3508864, 6711936)  ushort[100096*64] bf16 z (padded rows)
//  h2b       : [6711936, 8311968)  ushort[(N+1)*64]
//  temp      : [8311968, 10409120) uint[256*8192]
// Total ~41.6 MB.

// K1: prep — dinv + premultiplied bf16 entity rows (+ zero row at N_ENT)
__global__ __launch_bounds__(256) void prep_k(const float* __restrict__ emb,
                                              const int* __restrict__ degi,
                                              float* __restrict__ dinv,
                                              unsigned short* __restrict__ emb_b) {
    int gt   = blockIdx.x * 256 + threadIdx.x;
    int n    = gt >> 6;
    int lane = threadIdx.x & 63;
    if (n > N_ENT) return;
    if (n == N_ENT) { emb_b[(size_t)n * 64 + lane] = 0; return; }
    float v = emb[(size_t)n * 64 + lane];
    float s = v * v;
#pragma unroll
    for (int o = 32; o > 0; o >>= 1) s += __shfl_xor(s, o, 64);
    float nrm = sqrtf(s);
    float sc  = nrm > 1.0f ? 1.0f / nrm : 1.0f;
    float dv  = 1.0f / sqrtf((float)(degi[n] + 1));
    if (lane == 0) dinv[n] = dv;
    emb_b[(size_t)n * 64 + lane] = f2b(sc * dv * v);
}

// K0a: gcursor init to fixed bucket bases
__global__ __launch_bounds__(256) void ginit_k(int* __restrict__ gcursor) {
    gcursor[threadIdx.x] = threadIdx.x * BUCKCAP;
}

// K0p: pack W1/W2 into MFMA B-operand lane order (bf16).
// B-frag for mfma_f32_16x16x32_bf16: lane holds B[k = quad*8+j][n = lane&15].
// w1p entry e=(ct*2+s)*64+lane packs W1[s*32+quad*8+j][ct*16+li], j=0..7.
// w2p entry e=(ct*4+s)*64+lane packs W2[s*32+quad*8+j][ct*16+li].
__global__ __launch_bounds__(256) void packw_k(const float* __restrict__ W1g,
                                               const float* __restrict__ W2g,
                                               uint4* __restrict__ w1p,
                                               uint4* __restrict__ w2p) {
    int t = blockIdx.x * 256 + threadIdx.x;   // grid 8 -> 2048 threads
    int e    = t & 1023;
    int lane = e & 63, cs = e >> 6;
    int li   = lane & 15, quad = lane >> 4;
    unsigned short v[8];
    if (t < 1024) {
        int ct = cs >> 1, s = cs & 1;
        int kb = s * 32 + quad * 8;
        int n  = ct * 16 + li;
#pragma unroll
        for (int j = 0; j < 8; ++j) v[j] = f2b(W1g[(kb + j) * 128 + n]);
        uint4 p;
        p.x = (unsigned)v[0] | ((unsigned)v[1] << 16);
        p.y = (unsigned)v[2] | ((unsigned)v[3] << 16);
        p.z = (unsigned)v[4] | ((unsigned)v[5] << 16);
        p.w = (unsigned)v[6] | ((unsigned)v[7] << 16);
        w1p[e] = p;
    } else {
        int ct = cs >> 2, s = cs & 3;
        int kb = s * 32 + quad * 8;
        int n  = ct * 16 + li;
#pragma unroll
        for (int j = 0; j < 8; ++j) v[j] = f2b(W2g[(kb + j) * 64 + n]);
        uint4 p;
        p.x = (unsigned)v[0] | ((unsigned)v[1] << 16);
        p.y = (unsigned)v[2] | ((unsigned)v[3] << 16);
        p.z = (unsigned)v[4] | ((unsigned)v[5] << 16);
        p.w = (unsigned)v[6] | ((unsigned)v[7] << 16);
        w2p[e] = p;
    }
}

// K0b: bucket binning into fixed-capacity regions
__global__ __launch_bounds__(256) void bin_k(const int* __restrict__ edges,
                                             int* __restrict__ gcursor,
                                             unsigned int* __restrict__ temp) {
    __shared__ int cnt[NBUCK];
    __shared__ int gb[NBUCK];
    __shared__ int off[NBUCK];
    int tid  = threadIdx.x;
    int base = blockIdx.x * TILE;
    int sv[16], dv[16], bv[16];
    cnt[tid] = 0;
    __syncthreads();
#pragma unroll
    for (int i = 0; i < 16; ++i) {
        int e = base + i * 256 + tid;
        if (e < NEDGE) {
            sv[i] = edges[e];
            dv[i] = edges[NEDGE + e];
            bv[i] = dv[i] / KNODE;
            atomicAdd(&cnt[bv[i]], 1);
        } else {
            bv[i] = -1;
        }
    }
    __syncthreads();
    if (cnt[tid] > 0) gb[tid] = atomicAdd(&gcursor[tid], cnt[tid]);
    off[tid] = 0;
    __syncthreads();
#pragma unroll
    for (int i = 0; i < 16; ++i) {
        int b = bv[i];
        if (b >= 0) {
            int p  = atomicAdd(&off[b], 1);
            int dl = dv[i] - b * KNODE;
            temp[gb[b] + p] = ((unsigned int)sv[i] << 9) | (unsigned int)dl;
        }
    }
}

// K0c: per-bucket degree histogram from binned temp
__global__ __launch_bounds__(256) void count_k(const unsigned int* __restrict__ temp,
                                               const int* __restrict__ gcursor,
                                               int* __restrict__ degi) {
    __shared__ int cnt[KNODE];
    int b     = blockIdx.x;
    int node0 = b * KNODE;
    int nn    = N_ENT - node0; if (nn > KNODE) nn = KNODE;
    for (int i = threadIdx.x; i < KNODE; i += 256) cnt[i] = 0;
    __syncthreads();
    int tbeg = b * BUCKCAP;
    int tend = gcursor[b];
    for (int idx = tbeg + threadIdx.x; idx < tend; idx += 256)
        atomicAdd(&cnt[temp[idx] & 511u], 1);
    __syncthreads();
    for (int i = threadIdx.x; i < nn; i += 256) degi[node0 + i] = cnt[i];
}

// K3a/b/c: hierarchical exclusive scan of degi -> row_start
__global__ __launch_bounds__(256) void scan_partials(const int* __restrict__ degi,
                                                     int* __restrict__ partials) {
    __shared__ int ws[4];
    int i = blockIdx.x * 256 + threadIdx.x;
    int v = (i < N_ENT) ? degi[i] : 0;
#pragma unroll
    for (int o = 32; o > 0; o >>= 1) v += __shfl_xor(v, o, 64);
    if ((threadIdx.x & 63) == 0) ws[threadIdx.x >> 6] = v;
    __syncthreads();
    if (threadIdx.x == 0) partials[blockIdx.x] = ws[0] + ws[1] + ws[2] + ws[3];
}

__global__ __launch_bounds__(512) void scan_offsets(int* __restrict__ partials,
                                                    int* __restrict__ row_start) {
    __shared__ int ts[512];
    int t = threadIdx.x;
    int v = (t < NBLK_SCAN) ? partials[t] : 0;
    ts[t] = v;
    __syncthreads();
    for (int off = 1; off < 512; off <<= 1) {
        int x = (t >= off) ? ts[t - off] : 0;
        __syncthreads();
        ts[t] += x;
        __syncthreads();
    }
    if (t < NBLK_SCAN) partials[t] = ts[t] - v;
    if (t == 0) row_start[N_ENT] = NEDGE;
}

__global__ __launch_bounds__(256) void scan_apply(const int* __restrict__ degi,
                                                  const int* __restrict__ partials,
                                                  int* __restrict__ row_start) {
    __shared__ int ts[256];
    int t = threadIdx.x;
    int i = blockIdx.x * 256 + t;
    int v = (i < N_ENT) ? degi[i] : 0;
    ts[t] = v;
    __syncthreads();
    for (int off = 1; off < 256; off <<= 1) {
        int x = (t >= off) ? ts[t - off] : 0;
        __syncthreads();
        ts[t] += x;
        __syncthreads();
    }
    if (i < N_ENT) row_start[i] = ts[t] - v + partials[blockIdx.x];
}

// K4b: within-bucket placement
__global__ __launch_bounds__(256) void unbin_k(const unsigned int* __restrict__ temp,
                                               const int* __restrict__ gcursor,
                                               const int* __restrict__ row_start,
                                               int* __restrict__ srcs) {
    __shared__ int cur[KNODE];
    int b     = blockIdx.x;
    int node0 = b * KNODE;
    int nn    = N_ENT - node0; if (nn > KNODE) nn = KNODE;
    for (int i = threadIdx.x; i < nn; i += 256) cur[i] = row_start[node0 + i];
    __syncthreads();
    int tbeg = b * BUCKCAP;
    int tend = gcursor[b];
    for (int idx = tbeg + threadIdx.x; idx < tend; idx += 256) {
        unsigned int v = temp[idx];
        int dl = (int)(v & 511u);
        int s  = (int)(v >> 9);
        int pos = atomicAdd(&cur[dl], 1);
        srcs[pos] = s;
    }
}

// K5: layer-1 aggregate, 4 edges per gather instruction; bf16 output rows.
__global__ __launch_bounds__(256) void reduce1_k(const int* __restrict__ row_start,
                                                 const int* __restrict__ srcs,
                                                 const unsigned short* __restrict__ emb_b,
                                                 const float* __restrict__ dinv,
                                                 unsigned short* __restrict__ zb) {
    int gt   = blockIdx.x * 256 + threadIdx.x;
    int dst  = gt >> 6;
    int lane = threadIdx.x & 63;
    int sub  = lane >> 4;
    int li   = lane & 15;
    int beg = row_start[dst];
    int end = row_start[dst + 1];
    float4 acc = make_float4(0.f, 0.f, 0.f, 0.f);
    for (int base = beg; base < end; base += 64) {
        int cnt = end - base; if (cnt > 64) cnt = 64;
        int s_v = (base + lane < end) ? srcs[base + lane] : N_ENT;
        for (int jj = 0; jj < cnt; jj += 16) {
            int s0 = __shfl(s_v, jj + sub,      64);
            int s1 = __shfl(s_v, jj + 4 + sub,  64);
            int s2 = __shfl(s_v, jj + 8 + sub,  64);
            int s3 = __shfl(s_v, jj + 12 + sub, 64);
            uint2 p0 = *(const uint2*)(emb_b + (size_t)s0 * 64 + li * 4);
            uint2 p1 = *(const uint2*)(emb_b + (size_t)s1 * 64 + li * 4);
            uint2 p2 = *(const uint2*)(emb_b + (size_t)s2 * 64 + li * 4);
            uint2 p3 = *(const uint2*)(emb_b + (size_t)s3 * 64 + li * 4);
            acc.x += blo(p0.x) + blo(p1.x) + blo(p2.x) + blo(p3.x);
            acc.y += bhi(p0.x) + bhi(p1.x) + bhi(p2.x) + bhi(p3.x);
            acc.z += blo(p0.y) + blo(p1.y) + blo(p2.y) + blo(p3.y);
            acc.w += bhi(p0.y) + bhi(p1.y) + bhi(p2.y) + bhi(p3.y);
        }
    }
    acc.x += __shfl_xor(acc.x, 16, 64); acc.y += __shfl_xor(acc.y, 16, 64);
    acc.z += __shfl_xor(acc.z, 16, 64); acc.w += __shfl_xor(acc.w, 16, 64);
    acc.x += __shfl_xor(acc.x, 32, 64); acc.y += __shfl_xor(acc.y, 32, 64);
    acc.z += __shfl_xor(acc.z, 32, 64); acc.w += __shfl_xor(acc.w, 32, 64);
    if (lane < 16) {
        uint2 po = *(const uint2*)(emb_b + (size_t)dst * 64 + li * 4);
        float dv = dinv[dst];
        unsigned int h0 = f2b(dv * (acc.x + blo(po.x)));
        unsigned int h1 = f2b(dv * (acc.y + bhi(po.x)));
        unsigned int h2 = f2b(dv * (acc.z + blo(po.y)));
        unsigned int h3 = f2b(dv * (acc.w + bhi(po.y)));
        uint2 p;
        p.x = h0 | (h1 << 16);
        p.y = h2 | (h3 << 16);
        *(uint2*)(zb + (size_t)dst * 64 + li * 4) = p;
    }
}

// K6: fused MFMA MLP: h2b = bf16(dinv * (relu(zb@W1 + b1) @ W2)).
// One wave per 16-row strip, 4 strips per block. MFMA 16x16x32_bf16:
//   A-frag: lane holds A[m=lane&15][k=quad*8+j]     [m120-verified layout]
//   C/D   : lane holds D[row=quad*4+r][col=lane&15] [m89/m91]
// y1 (relu, bf16) round-trips through per-wave LDS between phases; h2b
// written via LDS transpose for coalesced uint4 stores.
// [R13 lesson: VALU GEMM pair was ~90us, 3x above FMA model — matmul-shaped
//  work belongs on the matrix pipe; this kernel is I/O-bound at ~77 MB.]
__global__ __launch_bounds__(256) void mlp_k(const unsigned short* __restrict__ zb,
                                             const uint4* __restrict__ w1p,
                                             const float* __restrict__ b1,
                                             const uint4* __restrict__ w2p,
                                             const float* __restrict__ dinv,
                                             unsigned short* __restrict__ h2b) {
    __shared__ unsigned short y1s[4][16 * 136];   // per-wave y1 strip (pad 136)
    __shared__ unsigned short h2s[4][16 * 64];    // per-wave output strip
    int tid  = threadIdx.x;
    int w    = tid >> 6, lane = tid & 63;
    int li   = lane & 15, quad = lane >> 4;
    int r0   = blockIdx.x * 64 + w * 16;
    // phase-1 A frags (zb padded to 100096 rows; garbage rows masked at store)
    uint4 a0u = *(const uint4*)(zb + (size_t)(r0 + li) * 64 + quad * 8);
    uint4 a1u = *(const uint4*)(zb + (size_t)(r0 + li) * 64 + 32 + quad * 8);
    bf16x8 a0 = *(bf16x8*)&a0u;
    bf16x8 a1 = *(bf16x8*)&a1u;
    unsigned short* ys = y1s[w];
#pragma unroll
    for (int ct = 0; ct < 8; ++ct) {
        uint4 b0u = w1p[(ct * 2 + 0) * 64 + lane];
        uint4 b1u = w1p[(ct * 2 + 1) * 64 + lane];
        f32x4 acc = {0.f, 0.f, 0.f, 0.f};
        acc = __builtin_amdgcn_mfma_f32_16x16x32_bf16(a0, *(bf16x8*)&b0u, acc, 0, 0, 0);
        acc = __builtin_amdgcn_mfma_f32_16x16x32_bf16(a1, *(bf16x8*)&b1u, acc, 0, 0, 0);
        float bias = b1[ct * 16 + li];
#pragma unroll
        for (int r = 0; r < 4; ++r)
            ys[(quad * 4 + r) * 136 + ct * 16 + li] = f2b(fmaxf(acc[r] + bias, 0.f));
    }
    __syncthreads();
    // phase-2 A frags from LDS (A[m=li][k=s*32+quad*8+j])
    bf16x8 a2[4];
#pragma unroll
    for (int s = 0; s < 4; ++s) {
        uint4 au = *(const uint4*)(ys + li * 136 + s * 32 + quad * 8);
        a2[s] = *(bf16x8*)&au;
    }
    float dvr[4];
#pragma unroll
    for (int r = 0; r < 4; ++r) {
        int grow = r0 + quad * 4 + r;
        dvr[r] = (grow < N_ENT) ? dinv[grow] : 0.f;
    }
    unsigned short* hs = h2s[w];
#pragma unroll
    for (int ct = 0; ct < 4; ++ct) {
        f32x4 acc = {0.f, 0.f, 0.f, 0.f};
#pragma unroll
        for (int s = 0; s < 4; ++s) {
            uint4 bu = w2p[(ct * 4 + s) * 64 + lane];
            acc = __builtin_amdgcn_mfma_f32_16x16x32_bf16(a2[s], *(bf16x8*)&bu, acc, 0, 0, 0);
        }
#pragma unroll
        for (int r = 0; r < 4; ++r)
            hs[(quad * 4 + r) * 64 + ct * 16 + li] = f2b(acc[r] * dvr[r]);
    }
    __syncthreads();
    // coalesced store of the strip (2 uint4 per lane); zero row at N_ENT
#pragma unroll
    for (int q = 0; q < 2; ++q) {
        int t4   = lane * 2 + q;       // uint4 index within strip (0..127)
        int rl   = t4 >> 3;
        int c0   = (t4 & 7) * 8;
        int grow = r0 + rl;
        if (grow < N_ENT) {
            *(uint4*)(h2b + (size_t)grow * 64 + c0) = *(const uint4*)(hs + rl * 64 + c0);
        } else if (grow == N_ENT) {
            uint4 zz; zz.x = 0u; zz.y = 0u; zz.z = 0u; zz.w = 0u;
            *(uint4*)(h2b + (size_t)grow * 64 + c0) = zz;
        }
    }
}

// K8: fused layer-2 aggregate + final dot for the 8192 batch items.
__global__ __launch_bounds__(256) void reduce2f_k(const int* __restrict__ u,
                                                  const int* __restrict__ iidx,
                                                  const float* __restrict__ uemb,
                                                  const int* __restrict__ row_start,
                                                  const int* __restrict__ srcs,
                                                  const unsigned short* __restrict__ h2b,
                                                  const float* __restrict__ dinv,
                                                  const float* __restrict__ b2,
                                                  float* __restrict__ out) {
    int gt   = blockIdx.x * 256 + threadIdx.x;
    int b    = gt >> 6;
    int lane = threadIdx.x & 63;
    int sub  = lane >> 4;
    int li   = lane & 15;
    int dst = iidx[b];
    int beg = row_start[dst];
    int end = row_start[dst + 1];
    float4 acc = make_float4(0.f, 0.f, 0.f, 0.f);
    for (int base = beg; base < end; base += 64) {
        int cnt = end - base; if (cnt > 64) cnt = 64;
        int s_v = (base + lane < end) ? srcs[base + lane] : N_ENT;
        for (int jj = 0; jj < cnt; jj += 16) {
            int s0 = __shfl(s_v, jj + sub,      64);
            int s1 = __shfl(s_v, jj + 4 + sub,  64);
            int s2 = __shfl(s_v, jj + 8 + sub,  64);
            int s3 = __shfl(s_v, jj + 12 + sub, 64);
            uint2 p0 = *(const uint2*)(h2b + (size_t)s0 * 64 + li * 4);
            uint2 p1 = *(const uint2*)(h2b + (size_t)s1 * 64 + li * 4);
            uint2 p2 = *(const uint2*)(h2b + (size_t)s2 * 64 + li * 4);
            uint2 p3 = *(const uint2*)(h2b + (size_t)s3 * 64 + li * 4);
            acc.x += blo(p0.x) + blo(p1.x) + blo(p2.x) + blo(p3.x);
            acc.y += bhi(p0.x) + bhi(p1.x) + bhi(p2.x) + bhi(p3.x);
            acc.z += blo(p0.y) + blo(p1.y) + blo(p2.y) + blo(p3.y);
            acc.w += bhi(p0.y) + bhi(p1.y) + bhi(p2.y) + bhi(p3.y);
        }
    }
    acc.x += __shfl_xor(acc.x, 16, 64); acc.y += __shfl_xor(acc.y, 16, 64);
    acc.z += __shfl_xor(acc.z, 16, 64); acc.w += __shfl_xor(acc.w, 16, 64);
    acc.x += __shfl_xor(acc.x, 32, 64); acc.y += __shfl_xor(acc.y, 32, 64);
    acc.z += __shfl_xor(acc.z, 32, 64); acc.w += __shfl_xor(acc.w, 32, 64);
    float s1 = 0.f, s2 = 0.f;
    if (lane < 16) {
        uint2 po = *(const uint2*)(h2b + (size_t)dst * 64 + li * 4);
        float dv = dinv[dst];
        float4 bb = *(const float4*)(b2 + li * 4);
        float4 z2v;
        z2v.x = dv * (acc.x + blo(po.x)) + bb.x;
        z2v.y = dv * (acc.y + bhi(po.x)) + bb.y;
        z2v.z = dv * (acc.z + blo(po.y)) + bb.z;
        z2v.w = dv * (acc.w + bhi(po.y)) + bb.w;
        float4 ue = *(const float4*)(uemb + (size_t)u[b] * 64 + li * 4);
        s1 = ue.x * ue.x + ue.y * ue.y + ue.z * ue.z + ue.w * ue.w;
        s2 = ue.x * z2v.x + ue.y * z2v.y + ue.z * z2v.z + ue.w * z2v.w;
    }
#pragma unroll
    for (int o = 8; o > 0; o >>= 1) {
        s1 += __shfl_xor(s1, o, 64);
        s2 += __shfl_xor(s2, o, 64);
    }
    if (lane == 0) {
        float nrm = sqrtf(s1);
        float sc  = nrm > 1.0f ? 1.0f / nrm : 1.0f;
        float uv  = s2 * sc;
        out[b] = 1.0f / (1.0f + expf(-uv));
    }
}

// ---------------------------------------------------------------------------
extern "C" void kernel_launch(void* const* d_in, const int* in_sizes, int n_in,
                              void* d_out, int out_size, void* d_ws, size_t ws_size,
                              hipStream_t stream) {
    const int*   u          = (const int*)d_in[0];
    const int*   iidx       = (const int*)d_in[1];
    const int*   edges      = (const int*)d_in[2];
    const float* user_emb   = (const float*)d_in[3];
    const float* entity_emb = (const float*)d_in[4];
    const float* W1         = (const float*)d_in[5];
    const float* b1         = (const float*)d_in[6];
    const float* W2         = (const float*)d_in[7];
    const float* b2         = (const float*)d_in[8];
    float*       out        = (float*)d_out;

    char* ws = (char*)d_ws;
    int*            degi      = (int*)           (ws);
    float*          dinv      = (float*)         (ws + 100000u * 4);
    int*            row_start = (int*)           (ws + 200000u * 4);
    int*            gcursor   = (int*)           (ws + 300004u * 4);
    int*            partials  = (int*)           (ws + 300264u * 4);
    uint4*          w1p       = (uint4*)         (ws + 300656u * 4);
    uint4*          w2p       = (uint4*)         (ws + 304752u * 4);
    int*            srcs      = (int*)           (ws + 308848u * 4);
    unsigned short* emb_b     = (unsigned short*)(ws + 1908848u * 4);  // (N+1)*64
    unsigned short* zb        = (unsigned short*)(ws + 3508864u * 4);  // 100096*64
    unsigned short* h2b       = (unsigned short*)(ws + 6711936u * 4);  // (N+1)*64
    unsigned int*   temp      = (unsigned int*)  (ws + 8311968u * 4);

    ginit_k<<<1, 256, 0, stream>>>(gcursor);
    packw_k<<<8, 256, 0, stream>>>(W1, W2, w1p, w2p);
    bin_k<<<NTILE, 256, 0, stream>>>(edges, gcursor, temp);
    count_k<<<NBUCK, 256, 0, stream>>>(temp, gcursor, degi);

    prep_k<<<N_ENT * 64 / 256 + 1, 256, 0, stream>>>(entity_emb, degi, dinv, emb_b);

    scan_partials<<<NBLK_SCAN, 256, 0, stream>>>(degi, partials);
    scan_offsets<<<1, 512, 0, stream>>>(partials, row_start);
    scan_apply<<<NBLK_SCAN, 256, 0, stream>>>(degi, partials, row_start);

    unbin_k<<<NBUCK, 256, 0, stream>>>(temp, gcursor, row_start, srcs);

    reduce1_k<<<N_ENT * 64 / 256, 256, 0, stream>>>(row_start, srcs, emb_b, dinv, zb);
    mlp_k<<<NBLK_G, 256, 0, stream>>>(zb, w1p, b1, w2p, dinv, h2b);

    reduce2f_k<<<BATCH * 64 / 256, 256, 0, stream>>>(u, iidx, user_emb, row_start,
                                                     srcs, h2b, dinv, b2, out);
}